// Round 1
// baseline (2181.339 us; speedup 1.0000x reference)
//
#include <hip/hip_runtime.h>

// WalletGNN: 2-layer GCN, N=100000 nodes, E=800000 edges, 128 -> 128 -> 64.
// Inputs: x[N,128] f32, edge_index[2,E] i32, W1[128,128], b1[128], W2[128,64], b2[64]
// Output: [N,64] f32.
//
// Math fold: agg[d] = dinv[d] * ( sum_{e:dst=d} (h[src]*dinv[src]) + h[d]*dinv[d] )
// -> GEMM epilogue scales rows by dinv and writes to both the scatter source
//    (H) and the accumulator (self-loop term), scatter adds unscaled rows,
//    finish kernel applies dinv[d] scale + bias (+ ELU for layer 1).

__global__ __launch_bounds__(256) void k_init_deg(float* __restrict__ deg, int N) {
    int i = blockIdx.x * 256 + threadIdx.x;
    if (i < N) deg[i] = 1.0f;   // self-loop
}

__global__ __launch_bounds__(256) void k_count(const int* __restrict__ dst,
                                               float* __restrict__ deg, int E) {
    int i = blockIdx.x * 256 + threadIdx.x;
    if (i < E) atomicAdd(&deg[dst[i]], 1.0f);
}

__global__ __launch_bounds__(256) void k_rsqrt(float* __restrict__ dinv, int N) {
    int i = blockIdx.x * 256 + threadIdx.x;
    if (i < N) dinv[i] = rsqrtf(dinv[i]);
}

// C0[r][:] = C1[r][:] = dinv[r] * (A[r][:] @ B)   ; K fixed = 128
// BM=64 rows/block, 256 threads, each thread TM=8 x TN cols.
template<int BN, int TN>
__global__ __launch_bounds__(256) void k_gemm(const float* __restrict__ A,
        const float* __restrict__ B, const float* __restrict__ dinv,
        float* __restrict__ C0, float* __restrict__ C1, int M) {
    constexpr int BM = 64, BK = 32, TM = 8;
    constexpr int NB4 = BN / 4;
    __shared__ float sA[BM][BK];
    __shared__ float sB[BK][BN];
    const int tid  = threadIdx.x;
    const int tcol = tid & 31;    // 32 col groups
    const int trow = tid >> 5;    // 8 row groups
    const int row0 = blockIdx.x * BM;

    float acc[TM][TN];
#pragma unroll
    for (int i = 0; i < TM; ++i)
#pragma unroll
        for (int j = 0; j < TN; ++j) acc[i][j] = 0.0f;

    const int ar = tid >> 3;          // 0..31
    const int ac = (tid & 7) << 2;    // 0,4,..,28

    for (int kk = 0; kk < 128; kk += BK) {
        // ---- A tile: 64x32 ----
        {
            int g0 = row0 + ar, g1 = row0 + ar + 32;
            float4 v0 = make_float4(0.f, 0.f, 0.f, 0.f), v1 = v0;
            if (g0 < M) v0 = *(const float4*)&A[(size_t)g0 * 128 + kk + ac];
            if (g1 < M) v1 = *(const float4*)&A[(size_t)g1 * 128 + kk + ac];
            *(float4*)&sA[ar][ac]      = v0;
            *(float4*)&sA[ar + 32][ac] = v1;
        }
        // ---- B tile: 32xBN ----
#pragma unroll
        for (int p = 0; p < (BK * NB4) / 256; ++p) {
            int f = tid + p * 256;
            int r = f / NB4;
            int c = (f % NB4) * 4;
            *(float4*)&sB[r][c] = *(const float4*)&B[(size_t)(kk + r) * BN + c];
        }
        __syncthreads();
#pragma unroll
        for (int k = 0; k < BK; ++k) {
            float a[TM];
#pragma unroll
            for (int i = 0; i < TM; ++i) a[i] = sA[trow * TM + i][k];
            if constexpr (TN == 4) {
                float4 bv = *(const float4*)&sB[k][tcol * 4];
#pragma unroll
                for (int i = 0; i < TM; ++i) {
                    acc[i][0] = fmaf(a[i], bv.x, acc[i][0]);
                    acc[i][1] = fmaf(a[i], bv.y, acc[i][1]);
                    acc[i][2] = fmaf(a[i], bv.z, acc[i][2]);
                    acc[i][3] = fmaf(a[i], bv.w, acc[i][3]);
                }
            } else {
                float2 bv = *(const float2*)&sB[k][tcol * 2];
#pragma unroll
                for (int i = 0; i < TM; ++i) {
                    acc[i][0] = fmaf(a[i], bv.x, acc[i][0]);
                    acc[i][1] = fmaf(a[i], bv.y, acc[i][1]);
                }
            }
        }
        __syncthreads();
    }

#pragma unroll
    for (int i = 0; i < TM; ++i) {
        int r = row0 + trow * TM + i;
        if (r < M) {
            float s = dinv[r];
            if constexpr (TN == 4) {
                float4 o = make_float4(acc[i][0] * s, acc[i][1] * s,
                                       acc[i][2] * s, acc[i][3] * s);
                *(float4*)&C0[(size_t)r * BN + tcol * 4] = o;
                *(float4*)&C1[(size_t)r * BN + tcol * 4] = o;
            } else {
                float2 o = make_float2(acc[i][0] * s, acc[i][1] * s);
                *(float2*)&C0[(size_t)r * BN + tcol * 2] = o;
                *(float2*)&C1[(size_t)r * BN + tcol * 2] = o;
            }
        }
    }
}

// For each edge e, acc[dst[e]][:] += H[src[e]][:]   (one thread per float4 chunk)
template<int D>
__global__ __launch_bounds__(256) void k_scatter(const float* __restrict__ H,
        const int* __restrict__ src, const int* __restrict__ dst,
        float* __restrict__ acc, int E) {
    constexpr int CH = D / 4;                 // chunks per edge
    constexpr int SH = (D == 128) ? 5 : 4;
    int idx = blockIdx.x * 256 + threadIdx.x;
    if (idx >= E * CH) return;
    int e = idx >> SH;
    int c = (idx & (CH - 1)) << 2;
    int s = src[e], d = dst[e];
    float4 v = *(const float4*)&H[(size_t)s * D + c];
    float* p = &acc[(size_t)d * D + c];
    atomicAdd(p + 0, v.x);
    atomicAdd(p + 1, v.y);
    atomicAdd(p + 2, v.z);
    atomicAdd(p + 3, v.w);
}

// Y[n][:] = dinv[n]*Y[n][:] + bias  (+ELU), in place. One thread per float4.
template<int D, bool ELU>
__global__ __launch_bounds__(256) void k_finish(float* __restrict__ Y,
        const float* __restrict__ dinv, const float* __restrict__ bias, int N) {
    constexpr int CH = D / 4;
    constexpr int SH = (D == 128) ? 5 : 4;
    int idx = blockIdx.x * 256 + threadIdx.x;
    if (idx >= N * CH) return;
    int n = idx >> SH;
    int c = (idx & (CH - 1)) << 2;
    float s = dinv[n];
    float4 v = *(const float4*)&Y[(size_t)n * D + c];
    float4 b = *(const float4*)&bias[c];
    float4 o;
    o.x = fmaf(v.x, s, b.x);
    o.y = fmaf(v.y, s, b.y);
    o.z = fmaf(v.z, s, b.z);
    o.w = fmaf(v.w, s, b.w);
    if (ELU) {
        o.x = o.x > 0.f ? o.x : expm1f(o.x);
        o.y = o.y > 0.f ? o.y : expm1f(o.y);
        o.z = o.z > 0.f ? o.z : expm1f(o.z);
        o.w = o.w > 0.f ? o.w : expm1f(o.w);
    }
    *(float4*)&Y[(size_t)n * D + c] = o;
}

extern "C" void kernel_launch(void* const* d_in, const int* in_sizes, int n_in,
                              void* d_out, int out_size, void* d_ws, size_t ws_size,
                              hipStream_t stream) {
    const float* x  = (const float*)d_in[0];
    const int*   ei = (const int*)d_in[1];
    const float* W1 = (const float*)d_in[2];
    const float* b1 = (const float*)d_in[3];
    const float* W2 = (const float*)d_in[4];
    const float* b2 = (const float*)d_in[5];
    float* out = (float*)d_out;

    const int N = in_sizes[0] / 128;   // 100000
    const int E = in_sizes[1] / 2;     // 800000
    const int* src = ei;
    const int* dst = ei + E;

    // workspace layout (floats): dinv | H1 (also reused as H2) | agg1
    float* dinv = (float*)d_ws;
    float* H1   = dinv + (1 << 17);            // pad N to 131072
    float* agg1 = H1 + (size_t)N * 128;
    // total: 131072 + 12.8M + 12.8M floats ~= 103 MB

    k_init_deg<<<(N + 255) / 256, 256, 0, stream>>>(dinv, N);
    k_count<<<(E + 255) / 256, 256, 0, stream>>>(dst, dinv, E);
    k_rsqrt<<<(N + 255) / 256, 256, 0, stream>>>(dinv, N);

    // Layer 1: H1 = agg1 = dinv .* (x @ W1)
    k_gemm<128, 4><<<(N + 63) / 64, 256, 0, stream>>>(x, W1, dinv, H1, agg1, N);
    k_scatter<128><<<(E * 32 + 255) / 256, 256, 0, stream>>>(H1, src, dst, agg1, E);
    k_finish<128, true><<<(N * 32 + 255) / 256, 256, 0, stream>>>(agg1, dinv, b1, N);

    // Layer 2: H2 (reuse H1 buf) = out_init = dinv .* (act @ W2)
    k_gemm<64, 2><<<(N + 63) / 64, 256, 0, stream>>>(agg1, W2, dinv, H1, out, N);
    k_scatter<64><<<(E * 16 + 255) / 256, 256, 0, stream>>>(H1, src, dst, out, E);
    k_finish<64, false><<<(N * 16 + 255) / 256, 256, 0, stream>>>(out, dinv, b2, N);
}

// Round 2
// 323.287 us; speedup vs baseline: 6.7474x; 6.7474x over previous
//
#include <hip/hip_runtime.h>

// WalletGNN: 2-layer GCN, N=100000, E=800000, 128 -> 128 -> 64, fp32.
// R2: atomic scatter replaced by CSR (by dst) + wave-per-node gather.
//   H[s]    = dinv[s] * (x[s] @ W)          (GEMM epilogue scale)
//   out[d]  = dinv[d] * (sum_{s in nbr(d)} H[s] + H[d]) + b   (+ELU layer 1)
// Self-loops handled analytically (the +H[d] term), not stored in CSR.

// ---------- CSR build ----------
__global__ __launch_bounds__(256) void k_zero(int* __restrict__ p, int n) {
    int i = blockIdx.x * 256 + threadIdx.x;
    if (i < n) p[i] = 0;
}

__global__ __launch_bounds__(256) void k_count(const int* __restrict__ dst,
                                               int* __restrict__ deg, int E) {
    int i = blockIdx.x * 256 + threadIdx.x;
    if (i < E) atomicAdd(&deg[dst[i]], 1);
}

__global__ __launch_bounds__(256) void k_part(const int* __restrict__ deg,
                                              int* __restrict__ part, int N) {
    __shared__ int s[256];
    int tid = threadIdx.x;
    int i = blockIdx.x * 256 + tid;
    s[tid] = (i < N) ? deg[i] : 0;
    __syncthreads();
    for (int o = 128; o > 0; o >>= 1) {
        if (tid < o) s[tid] += s[tid + o];
        __syncthreads();
    }
    if (tid == 0) part[blockIdx.x] = s[0];
}

__global__ __launch_bounds__(512) void k_scanpart(int* __restrict__ part, int nb) {
    __shared__ int s[512];
    int tid = threadIdx.x;
    int v = (tid < nb) ? part[tid] : 0;
    s[tid] = v;
    __syncthreads();
    for (int off = 1; off < 512; off <<= 1) {
        int t = (tid >= off) ? s[tid - off] : 0;
        __syncthreads();
        s[tid] += t;
        __syncthreads();
    }
    if (tid < nb) part[tid] = s[tid] - v;   // exclusive
}

// row_ptr[i] = global exclusive scan of deg; cursor (same buf as deg) = row_ptr;
// dinv[i] = rsqrt(deg+1)  (self-loop included in degree, excluded from CSR)
__global__ __launch_bounds__(256) void k_finalize(int* __restrict__ deg_cursor,
        const int* __restrict__ part, int* __restrict__ row_ptr,
        float* __restrict__ dinv, int N) {
    __shared__ int s[256];
    int tid = threadIdx.x;
    int i = blockIdx.x * 256 + tid;
    int v = (i < N) ? deg_cursor[i] : 0;
    s[tid] = v;
    __syncthreads();
    for (int off = 1; off < 256; off <<= 1) {
        int t = (tid >= off) ? s[tid - off] : 0;
        __syncthreads();
        s[tid] += t;
        __syncthreads();
    }
    if (i < N) {
        int ex = part[blockIdx.x] + s[tid] - v;
        row_ptr[i] = ex;
        deg_cursor[i] = ex;                   // becomes fill cursor
        dinv[i] = rsqrtf((float)v + 1.0f);
        if (i == N - 1) row_ptr[N] = ex + v;
    }
}

__global__ __launch_bounds__(256) void k_fill(const int* __restrict__ src,
        const int* __restrict__ dst, int* __restrict__ cursor,
        int* __restrict__ col, int E) {
    int e = blockIdx.x * 256 + threadIdx.x;
    if (e < E) {
        int pos = atomicAdd(&cursor[dst[e]], 1);
        col[pos] = src[e];
    }
}

// ---------- GEMM: C[r][:] = dinv[r] * (A[r][:] @ B), K = 128 ----------
template<int BN, int TN>
__global__ __launch_bounds__(256) void k_gemm(const float* __restrict__ A,
        const float* __restrict__ B, const float* __restrict__ dinv,
        float* __restrict__ C, int M) {
    constexpr int BM = 64, BK = 32, TM = 8;
    constexpr int NB4 = BN / 4;
    __shared__ float sA[BM][BK];
    __shared__ float sB[BK][BN];
    const int tid  = threadIdx.x;
    const int tcol = tid & 31;
    const int trow = tid >> 5;
    const int row0 = blockIdx.x * BM;

    float acc[TM][TN];
#pragma unroll
    for (int i = 0; i < TM; ++i)
#pragma unroll
        for (int j = 0; j < TN; ++j) acc[i][j] = 0.0f;

    const int ar = tid >> 3;
    const int ac = (tid & 7) << 2;

    for (int kk = 0; kk < 128; kk += BK) {
        {
            int g0 = row0 + ar, g1 = row0 + ar + 32;
            float4 v0 = make_float4(0.f, 0.f, 0.f, 0.f), v1 = v0;
            if (g0 < M) v0 = *(const float4*)&A[(size_t)g0 * 128 + kk + ac];
            if (g1 < M) v1 = *(const float4*)&A[(size_t)g1 * 128 + kk + ac];
            *(float4*)&sA[ar][ac]      = v0;
            *(float4*)&sA[ar + 32][ac] = v1;
        }
#pragma unroll
        for (int p = 0; p < (BK * NB4) / 256; ++p) {
            int f = tid + p * 256;
            int r = f / NB4;
            int c = (f % NB4) * 4;
            *(float4*)&sB[r][c] = *(const float4*)&B[(size_t)(kk + r) * BN + c];
        }
        __syncthreads();
#pragma unroll
        for (int k = 0; k < BK; ++k) {
            float a[TM];
#pragma unroll
            for (int i = 0; i < TM; ++i) a[i] = sA[trow * TM + i][k];
            if constexpr (TN == 4) {
                float4 bv = *(const float4*)&sB[k][tcol * 4];
#pragma unroll
                for (int i = 0; i < TM; ++i) {
                    acc[i][0] = fmaf(a[i], bv.x, acc[i][0]);
                    acc[i][1] = fmaf(a[i], bv.y, acc[i][1]);
                    acc[i][2] = fmaf(a[i], bv.z, acc[i][2]);
                    acc[i][3] = fmaf(a[i], bv.w, acc[i][3]);
                }
            } else {
                float2 bv = *(const float2*)&sB[k][tcol * 2];
#pragma unroll
                for (int i = 0; i < TM; ++i) {
                    acc[i][0] = fmaf(a[i], bv.x, acc[i][0]);
                    acc[i][1] = fmaf(a[i], bv.y, acc[i][1]);
                }
            }
        }
        __syncthreads();
    }

#pragma unroll
    for (int i = 0; i < TM; ++i) {
        int r = row0 + trow * TM + i;
        if (r < M) {
            float s = dinv[r];
            if constexpr (TN == 4) {
                float4 o = make_float4(acc[i][0] * s, acc[i][1] * s,
                                       acc[i][2] * s, acc[i][3] * s);
                *(float4*)&C[(size_t)r * BN + tcol * 4] = o;
            } else {
                float2 o = make_float2(acc[i][0] * s, acc[i][1] * s);
                *(float2*)&C[(size_t)r * BN + tcol * 2] = o;
            }
        }
    }
}

// ---------- gather: one wave per node ----------
template<int D, bool ELU>
__global__ __launch_bounds__(256) void k_gather(const float* __restrict__ H,
        const int* __restrict__ row_ptr, const int* __restrict__ col,
        const float* __restrict__ dinv, const float* __restrict__ bias,
        float* __restrict__ out, int N) {
    const int wave = threadIdx.x >> 6;
    const int lane = threadIdx.x & 63;
    const int n = blockIdx.x * 4 + wave;
    if (n >= N) return;
    const int beg = row_ptr[n], end = row_ptr[n + 1];

    if constexpr (D == 128) {
        const int c = lane * 2;
        float2 self = *(const float2*)&H[(size_t)n * 128 + c];
        float a0x = self.x, a0y = self.y, a1x = 0.f, a1y = 0.f;
        int j = beg;
        for (; j + 1 < end; j += 2) {
            int c0 = col[j], c1 = col[j + 1];
            float2 v0 = *(const float2*)&H[(size_t)c0 * 128 + c];
            float2 v1 = *(const float2*)&H[(size_t)c1 * 128 + c];
            a0x += v0.x; a0y += v0.y;
            a1x += v1.x; a1y += v1.y;
        }
        if (j < end) {
            int c0 = col[j];
            float2 v0 = *(const float2*)&H[(size_t)c0 * 128 + c];
            a0x += v0.x; a0y += v0.y;
        }
        float s = dinv[n];
        float2 b = *(const float2*)&bias[c];
        float ox = fmaf(a0x + a1x, s, b.x);
        float oy = fmaf(a0y + a1y, s, b.y);
        if (ELU) {
            ox = ox > 0.f ? ox : expm1f(ox);
            oy = oy > 0.f ? oy : expm1f(oy);
        }
        *(float2*)&out[(size_t)n * 128 + c] = make_float2(ox, oy);
    } else {
        float a0 = H[(size_t)n * 64 + lane], a1 = 0.f, a2 = 0.f, a3 = 0.f;
        int j = beg;
        for (; j + 3 < end; j += 4) {
            int c0 = col[j], c1 = col[j + 1], c2 = col[j + 2], c3 = col[j + 3];
            a0 += H[(size_t)c0 * 64 + lane];
            a1 += H[(size_t)c1 * 64 + lane];
            a2 += H[(size_t)c2 * 64 + lane];
            a3 += H[(size_t)c3 * 64 + lane];
        }
        for (; j < end; ++j) a0 += H[(size_t)col[j] * 64 + lane];
        float s = dinv[n];
        float o = fmaf((a0 + a1) + (a2 + a3), s, bias[lane]);
        if (ELU) o = o > 0.f ? o : expm1f(o);
        out[(size_t)n * 64 + lane] = o;
    }
}

extern "C" void kernel_launch(void* const* d_in, const int* in_sizes, int n_in,
                              void* d_out, int out_size, void* d_ws, size_t ws_size,
                              hipStream_t stream) {
    const float* x  = (const float*)d_in[0];
    const int*   ei = (const int*)d_in[1];
    const float* W1 = (const float*)d_in[2];
    const float* b1 = (const float*)d_in[3];
    const float* W2 = (const float*)d_in[4];
    const float* b2 = (const float*)d_in[5];
    float* out = (float*)d_out;

    const int N = in_sizes[0] / 128;   // 100000
    const int E = in_sizes[1] / 2;     // 800000
    const int* src = ei;
    const int* dst = ei + E;
    const int NB = (N + 255) / 256;    // 391 scan blocks (<=512)

    // workspace layout (16-element aligned)
    int* deg_cursor = (int*)d_ws;                         // N
    int* row_ptr    = deg_cursor + ((N + 15) & ~15);      // N+1
    int* part       = row_ptr + ((N + 1 + 15) & ~15);     // 512
    int* col        = part + 512;                         // E
    float* dinv     = (float*)(col + ((E + 15) & ~15));   // N
    float* H        = dinv + ((N + 15) & ~15);            // N*128 (layer2 reuses)
    float* act      = H + (size_t)N * 128;                // N*128

    // CSR build
    k_zero<<<NB, 256, 0, stream>>>(deg_cursor, N);
    k_count<<<(E + 255) / 256, 256, 0, stream>>>(dst, deg_cursor, E);
    k_part<<<NB, 256, 0, stream>>>(deg_cursor, part, N);
    k_scanpart<<<1, 512, 0, stream>>>(part, NB);
    k_finalize<<<NB, 256, 0, stream>>>(deg_cursor, part, row_ptr, dinv, N);
    k_fill<<<(E + 255) / 256, 256, 0, stream>>>(src, dst, deg_cursor, col, E);

    // Layer 1
    k_gemm<128, 4><<<(N + 63) / 64, 256, 0, stream>>>(x, W1, dinv, H, N);
    k_gather<128, true><<<(N + 3) / 4, 256, 0, stream>>>(H, row_ptr, col, dinv, b1, act, N);

    // Layer 2 (H buffer reused for H2[N,64])
    k_gemm<64, 2><<<(N + 63) / 64, 256, 0, stream>>>(act, W2, dinv, H, N);
    k_gather<64, false><<<(N + 3) / 4, 256, 0, stream>>>(H, row_ptr, col, dinv, b2, out, N);
}

// Round 3
// 254.825 us; speedup vs baseline: 8.5601x; 1.2687x over previous
//
#include <hip/hip_runtime.h>

// WalletGNN: 2-layer GCN, N=100000, E=800000, 128 -> 128 -> 64, fp32 in/out.
// R3: bf16 H/act + MFMA GEMMs (whole W^T resident in LDS, single sync),
//     wide gather (8 B/lane row slices, shfl-reduce across wave halves).

typedef __attribute__((ext_vector_type(8))) short bf16x8;
typedef __attribute__((ext_vector_type(4))) float f32x4;

static __device__ __forceinline__ unsigned short f2bf(float f) {
    unsigned u = __builtin_bit_cast(unsigned, f);
    u += 0x7fffu + ((u >> 16) & 1u);
    return (unsigned short)(u >> 16);
}
static __device__ __forceinline__ float bflo(unsigned u) {
    return __builtin_bit_cast(float, u << 16);
}
static __device__ __forceinline__ float bfhi(unsigned u) {
    return __builtin_bit_cast(float, u & 0xffff0000u);
}

// ---------- CSR build ----------
__global__ __launch_bounds__(256) void k_zero(int* __restrict__ p, int n) {
    int i = blockIdx.x * 256 + threadIdx.x;
    if (i < n) p[i] = 0;
}

__global__ __launch_bounds__(256) void k_count(const int* __restrict__ dst,
                                               int* __restrict__ deg, int E) {
    int i = blockIdx.x * 256 + threadIdx.x;
    if (i < E) atomicAdd(&deg[dst[i]], 1);
}

__global__ __launch_bounds__(256) void k_part(const int* __restrict__ deg,
                                              int* __restrict__ part, int N) {
    __shared__ int s[256];
    int tid = threadIdx.x;
    int i = blockIdx.x * 256 + tid;
    s[tid] = (i < N) ? deg[i] : 0;
    __syncthreads();
    for (int o = 128; o > 0; o >>= 1) {
        if (tid < o) s[tid] += s[tid + o];
        __syncthreads();
    }
    if (tid == 0) part[blockIdx.x] = s[0];
}

__global__ __launch_bounds__(512) void k_scanpart(int* __restrict__ part, int nb) {
    __shared__ int s[512];
    int tid = threadIdx.x;
    int v = (tid < nb) ? part[tid] : 0;
    s[tid] = v;
    __syncthreads();
    for (int off = 1; off < 512; off <<= 1) {
        int t = (tid >= off) ? s[tid - off] : 0;
        __syncthreads();
        s[tid] += t;
        __syncthreads();
    }
    if (tid < nb) part[tid] = s[tid] - v;   // exclusive
}

__global__ __launch_bounds__(256) void k_finalize(int* __restrict__ deg_cursor,
        const int* __restrict__ part, int* __restrict__ row_ptr,
        float* __restrict__ dinv, int N) {
    __shared__ int s[256];
    int tid = threadIdx.x;
    int i = blockIdx.x * 256 + tid;
    int v = (i < N) ? deg_cursor[i] : 0;
    s[tid] = v;
    __syncthreads();
    for (int off = 1; off < 256; off <<= 1) {
        int t = (tid >= off) ? s[tid - off] : 0;
        __syncthreads();
        s[tid] += t;
        __syncthreads();
    }
    if (i < N) {
        int ex = part[blockIdx.x] + s[tid] - v;
        row_ptr[i] = ex;
        deg_cursor[i] = ex;                   // becomes fill cursor
        dinv[i] = rsqrtf((float)v + 1.0f);    // +1 self-loop
        if (i == N - 1) row_ptr[N] = ex + v;
    }
}

__global__ __launch_bounds__(256) void k_fill(const int* __restrict__ src,
        const int* __restrict__ dst, int* __restrict__ cursor,
        int* __restrict__ col, int E) {
    int e = blockIdx.x * 256 + threadIdx.x;
    if (e < E) {
        int pos = atomicAdd(&cursor[dst[e]], 1);
        col[pos] = src[e];
    }
}

// ---------- W -> W^T bf16 ----------
__global__ __launch_bounds__(256) void k_prep_w(const float* __restrict__ W1,
        const float* __restrict__ W2, unsigned short* __restrict__ W1t,
        unsigned short* __restrict__ W2t) {
    int i = blockIdx.x * 256 + threadIdx.x;
    if (i < 128 * 128) {
        int n = i >> 7, k = i & 127;
        W1t[i] = f2bf(W1[k * 128 + n]);
    }
    int j = i - 128 * 128;
    if (j >= 0 && j < 64 * 128) {
        int n = j >> 7, k = j & 127;
        W2t[j] = f2bf(W2[k * 64 + n]);
    }
}

// ---------- MFMA GEMM: C[r][:] = bf16( dinv[r] * (A[r][:] @ B) ), K=128 ----------
// Wt is B transposed [NC][128] bf16. Block: 64 rows x NC cols, 4 waves.
// Wave w owns cols [w*NC/4, w*NC/4 + NC/4). Entire A-tile + Wt resident in LDS.
template<int NC, bool ABF16>
__global__ __launch_bounds__(256) void k_gemm(const void* __restrict__ Av,
        const unsigned short* __restrict__ Wt, const float* __restrict__ dinv,
        unsigned short* __restrict__ C, int M) {
    __shared__ unsigned short sA[64][136];   // +8 pad (16 B) kills bank conflicts
    __shared__ unsigned short sW[NC][136];
    const int tid  = threadIdx.x;
    const int lane = tid & 63;
    const int wave = tid >> 6;
    const int row0 = blockIdx.x * 64;

    if (ABF16) {
        const uint4* A = (const uint4*)Av;               // row = 16 uint4
#pragma unroll
        for (int p = 0; p < 4; ++p) {
            int c = tid + p * 256;
            int row = c >> 4, cc = c & 15;
            uint4 v = make_uint4(0u, 0u, 0u, 0u);
            if (row0 + row < M) v = A[(size_t)(row0 + row) * 16 + cc];
            *(uint4*)&sA[row][cc * 8] = v;
        }
    } else {
        const float* A = (const float*)Av;
#pragma unroll
        for (int p = 0; p < 8; ++p) {
            int c = tid + p * 256;
            int row = c >> 5, c4 = (c & 31) * 4;
            float4 v = make_float4(0.f, 0.f, 0.f, 0.f);
            if (row0 + row < M) v = *(const float4*)&A[(size_t)(row0 + row) * 128 + c4];
            ushort4 o;
            o.x = f2bf(v.x); o.y = f2bf(v.y); o.z = f2bf(v.z); o.w = f2bf(v.w);
            *(ushort4*)&sA[row][c4] = o;
        }
    }
    {
        const uint4* W4 = (const uint4*)Wt;              // [NC*16] uint4
#pragma unroll
        for (int p = 0; p < NC / 16; ++p) {
            int c = tid + p * 256;
            int n = c >> 4, cc = c & 15;
            *(uint4*)&sW[n][cc * 8] = W4[c];
        }
    }
    __syncthreads();

    constexpr int CT = NC / 64;                          // col 16-tiles per wave
    const int colbase = wave * (NC / 4);
    const int frow = lane & 15;
    const int fk   = (lane >> 4) * 8;

    f32x4 acc[4][CT];
#pragma unroll
    for (int rt = 0; rt < 4; ++rt)
#pragma unroll
        for (int ct = 0; ct < CT; ++ct) acc[rt][ct] = (f32x4){0.f, 0.f, 0.f, 0.f};

#pragma unroll
    for (int kk = 0; kk < 128; kk += 32) {
        bf16x8 a[4], b[CT];
#pragma unroll
        for (int rt = 0; rt < 4; ++rt)
            a[rt] = *(const bf16x8*)&sA[rt * 16 + frow][kk + fk];
#pragma unroll
        for (int ct = 0; ct < CT; ++ct)
            b[ct] = *(const bf16x8*)&sW[colbase + ct * 16 + frow][kk + fk];
#pragma unroll
        for (int rt = 0; rt < 4; ++rt)
#pragma unroll
            for (int ct = 0; ct < CT; ++ct)
                acc[rt][ct] = __builtin_amdgcn_mfma_f32_16x16x32_bf16(
                    a[rt], b[ct], acc[rt][ct], 0, 0, 0);
    }

    const int crow = (lane >> 4) * 4;
#pragma unroll
    for (int rt = 0; rt < 4; ++rt) {
        int grow = row0 + rt * 16 + crow;
#pragma unroll
        for (int r = 0; r < 4; ++r) {
            if (grow + r < M) {
                float s = dinv[grow + r];
#pragma unroll
                for (int ct = 0; ct < CT; ++ct) {
                    int gcol = colbase + ct * 16 + (lane & 15);
                    C[(size_t)(grow + r) * NC + gcol] = f2bf(acc[rt][ct][r] * s);
                }
            }
        }
    }
}

// ---------- gather, D=128 bf16: wave per node, halves take alternating nbrs ----------
template<bool ELU>
__global__ __launch_bounds__(256) void k_gather128(const unsigned* __restrict__ H,
        const int* __restrict__ row_ptr, const int* __restrict__ col,
        const float* __restrict__ dinv, const float* __restrict__ bias,
        unsigned* __restrict__ outbf, int N) {
    const int wave = threadIdx.x >> 6, lane = threadIdx.x & 63;
    const int n = blockIdx.x * 4 + wave;
    if (n >= N) return;
    const int beg = row_ptr[n];
    const int cnt = row_ptr[n + 1] - beg + 1;   // +1 = self (virtual t=0)
    const int half = lane >> 5;
    const int s = lane & 31;                    // cols 4s..4s+3
    float a0 = 0.f, a1 = 0.f, a2 = 0.f, a3 = 0.f;
    for (int t = half; t < cnt; t += 2) {
        int src = (t == 0) ? n : col[beg + t - 1];
        uint2 v = *(const uint2*)&H[(size_t)src * 64 + 2 * s];
        a0 += bflo(v.x); a1 += bfhi(v.x);
        a2 += bflo(v.y); a3 += bfhi(v.y);
    }
    a0 += __shfl_xor(a0, 32); a1 += __shfl_xor(a1, 32);
    a2 += __shfl_xor(a2, 32); a3 += __shfl_xor(a3, 32);
    if (half == 0) {
        float sc = dinv[n];
        float4 b = *(const float4*)&bias[4 * s];
        float o0 = fmaf(a0, sc, b.x), o1 = fmaf(a1, sc, b.y);
        float o2 = fmaf(a2, sc, b.z), o3 = fmaf(a3, sc, b.w);
        if (ELU) {
            o0 = o0 > 0.f ? o0 : expm1f(o0);
            o1 = o1 > 0.f ? o1 : expm1f(o1);
            o2 = o2 > 0.f ? o2 : expm1f(o2);
            o3 = o3 > 0.f ? o3 : expm1f(o3);
        }
        uint2 o;
        o.x = (unsigned)f2bf(o0) | ((unsigned)f2bf(o1) << 16);
        o.y = (unsigned)f2bf(o2) | ((unsigned)f2bf(o3) << 16);
        *(uint2*)&outbf[(size_t)n * 64 + 2 * s] = o;
    }
}

// ---------- gather, D=64 bf16 in, f32 out: quarter-wave row slices ----------
__global__ __launch_bounds__(256) void k_gather64(const unsigned* __restrict__ H,
        const int* __restrict__ row_ptr, const int* __restrict__ col,
        const float* __restrict__ dinv, const float* __restrict__ bias,
        float* __restrict__ out, int N) {
    const int wave = threadIdx.x >> 6, lane = threadIdx.x & 63;
    const int n = blockIdx.x * 4 + wave;
    if (n >= N) return;
    const int beg = row_ptr[n];
    const int cnt = row_ptr[n + 1] - beg + 1;
    const int q = lane >> 4;
    const int s = lane & 15;                    // cols 4s..4s+3
    float a0 = 0.f, a1 = 0.f, a2 = 0.f, a3 = 0.f;
    for (int t = q; t < cnt; t += 4) {
        int src = (t == 0) ? n : col[beg + t - 1];
        uint2 v = *(const uint2*)&H[(size_t)src * 32 + 2 * s];
        a0 += bflo(v.x); a1 += bfhi(v.x);
        a2 += bflo(v.y); a3 += bfhi(v.y);
    }
    a0 += __shfl_xor(a0, 16); a1 += __shfl_xor(a1, 16);
    a2 += __shfl_xor(a2, 16); a3 += __shfl_xor(a3, 16);
    a0 += __shfl_xor(a0, 32); a1 += __shfl_xor(a1, 32);
    a2 += __shfl_xor(a2, 32); a3 += __shfl_xor(a3, 32);
    if (q == 0) {
        float sc = dinv[n];
        float4 b = *(const float4*)&bias[4 * s];
        float4 o;
        o.x = fmaf(a0, sc, b.x); o.y = fmaf(a1, sc, b.y);
        o.z = fmaf(a2, sc, b.z); o.w = fmaf(a3, sc, b.w);
        *(float4*)&out[(size_t)n * 64 + 4 * s] = o;
    }
}

extern "C" void kernel_launch(void* const* d_in, const int* in_sizes, int n_in,
                              void* d_out, int out_size, void* d_ws, size_t ws_size,
                              hipStream_t stream) {
    const float* x  = (const float*)d_in[0];
    const int*   ei = (const int*)d_in[1];
    const float* W1 = (const float*)d_in[2];
    const float* b1 = (const float*)d_in[3];
    const float* W2 = (const float*)d_in[4];
    const float* b2 = (const float*)d_in[5];
    float* out = (float*)d_out;

    const int N = in_sizes[0] / 128;   // 100000
    const int E = in_sizes[1] / 2;     // 800000
    const int* src = ei;
    const int* dst = ei + E;
    const int NB = (N + 255) / 256;    // 391 (<512)
    const int NPAD = (N + 63) & ~63;   // 100032... pad to 64-mult

    // workspace layout (4-byte units, each region 64-aligned)
    unsigned off = 0;
    int* deg_cursor = (int*)d_ws + off;            off += NPAD + 64;
    int* row_ptr    = (int*)d_ws + off;            off += NPAD + 64;
    int* part       = (int*)d_ws + off;            off += 512;
    int* col        = (int*)d_ws + off;            off += (unsigned)((E + 63) & ~63);
    float* dinv     = (float*)d_ws + off;          off += NPAD + 64;
    unsigned short* W1t = (unsigned short*)((int*)d_ws + off); off += 8192;
    unsigned short* W2t = (unsigned short*)((int*)d_ws + off); off += 4096;
    unsigned* H     = (unsigned*)((int*)d_ws + off); off += (unsigned)N * 64 + 64;  // [N][128] bf16
    unsigned* act   = (unsigned*)((int*)d_ws + off);                                 // [N][128] bf16

    // CSR build + weight prep
    k_zero<<<NB, 256, 0, stream>>>(deg_cursor, N);
    k_count<<<(E + 255) / 256, 256, 0, stream>>>(dst, deg_cursor, E);
    k_part<<<NB, 256, 0, stream>>>(deg_cursor, part, N);
    k_scanpart<<<1, 512, 0, stream>>>(part, NB);
    k_finalize<<<NB, 256, 0, stream>>>(deg_cursor, part, row_ptr, dinv, N);
    k_fill<<<(E + 255) / 256, 256, 0, stream>>>(src, dst, deg_cursor, col, E);
    k_prep_w<<<96, 256, 0, stream>>>(W1, W2, W1t, W2t);

    // Layer 1: H = bf16(dinv .* (x @ W1)); act = bf16(ELU(dinv .* (gather H) + b1))
    k_gemm<128, false><<<(N + 63) / 64, 256, 0, stream>>>(x, W1t, dinv,
                                                          (unsigned short*)H, N);
    k_gather128<true><<<(N + 3) / 4, 256, 0, stream>>>(H, row_ptr, col, dinv, b1, act, N);

    // Layer 2: H2 (reuse H) = bf16(dinv .* (act @ W2)); out = dinv .* (gather H2) + b2
    k_gemm<64, true><<<(N + 63) / 64, 256, 0, stream>>>(act, W2t, dinv,
                                                        (unsigned short*)H, N);
    k_gather64<<<(N + 3) / 4, 256, 0, stream>>>(H, row_ptr, col, dinv, b2, out, N);
}

// Round 4
// 232.855 us; speedup vs baseline: 9.3678x; 1.0944x over previous
//
#include <hip/hip_runtime.h>

// WalletGNN: 2-layer GCN, N=100000, E=800000, 128 -> 128 -> 64, fp32 in/out.
// R4: gathers restructured for memory-level parallelism (4-deep / 2-deep
//     manual unroll, self-row hoisted), k_zero replaced by hipMemsetAsync.

typedef __attribute__((ext_vector_type(8))) short bf16x8;
typedef __attribute__((ext_vector_type(4))) float f32x4;

static __device__ __forceinline__ unsigned short f2bf(float f) {
    unsigned u = __builtin_bit_cast(unsigned, f);
    u += 0x7fffu + ((u >> 16) & 1u);
    return (unsigned short)(u >> 16);
}
static __device__ __forceinline__ float bflo(unsigned u) {
    return __builtin_bit_cast(float, u << 16);
}
static __device__ __forceinline__ float bfhi(unsigned u) {
    return __builtin_bit_cast(float, u & 0xffff0000u);
}

// ---------- CSR build ----------
__global__ __launch_bounds__(256) void k_count(const int* __restrict__ dst,
                                               int* __restrict__ deg, int E) {
    int i = blockIdx.x * 256 + threadIdx.x;
    if (i < E) atomicAdd(&deg[dst[i]], 1);
}

__global__ __launch_bounds__(256) void k_part(const int* __restrict__ deg,
                                              int* __restrict__ part, int N) {
    __shared__ int s[256];
    int tid = threadIdx.x;
    int i = blockIdx.x * 256 + tid;
    s[tid] = (i < N) ? deg[i] : 0;
    __syncthreads();
    for (int o = 128; o > 0; o >>= 1) {
        if (tid < o) s[tid] += s[tid + o];
        __syncthreads();
    }
    if (tid == 0) part[blockIdx.x] = s[0];
}

__global__ __launch_bounds__(512) void k_scanpart(int* __restrict__ part, int nb) {
    __shared__ int s[512];
    int tid = threadIdx.x;
    int v = (tid < nb) ? part[tid] : 0;
    s[tid] = v;
    __syncthreads();
    for (int off = 1; off < 512; off <<= 1) {
        int t = (tid >= off) ? s[tid - off] : 0;
        __syncthreads();
        s[tid] += t;
        __syncthreads();
    }
    if (tid < nb) part[tid] = s[tid] - v;   // exclusive
}

__global__ __launch_bounds__(256) void k_finalize(int* __restrict__ deg_cursor,
        const int* __restrict__ part, int* __restrict__ row_ptr,
        float* __restrict__ dinv, int N) {
    __shared__ int s[256];
    int tid = threadIdx.x;
    int i = blockIdx.x * 256 + tid;
    int v = (i < N) ? deg_cursor[i] : 0;
    s[tid] = v;
    __syncthreads();
    for (int off = 1; off < 256; off <<= 1) {
        int t = (tid >= off) ? s[tid - off] : 0;
        __syncthreads();
        s[tid] += t;
        __syncthreads();
    }
    if (i < N) {
        int ex = part[blockIdx.x] + s[tid] - v;
        row_ptr[i] = ex;
        deg_cursor[i] = ex;                   // becomes fill cursor
        dinv[i] = rsqrtf((float)v + 1.0f);    // +1 self-loop
        if (i == N - 1) row_ptr[N] = ex + v;
    }
}

__global__ __launch_bounds__(256) void k_fill(const int* __restrict__ src,
        const int* __restrict__ dst, int* __restrict__ cursor,
        int* __restrict__ col, int E) {
    int e = blockIdx.x * 256 + threadIdx.x;
    if (e < E) {
        int pos = atomicAdd(&cursor[dst[e]], 1);
        col[pos] = src[e];
    }
}

// ---------- W -> W^T bf16 ----------
__global__ __launch_bounds__(256) void k_prep_w(const float* __restrict__ W1,
        const float* __restrict__ W2, unsigned short* __restrict__ W1t,
        unsigned short* __restrict__ W2t) {
    int i = blockIdx.x * 256 + threadIdx.x;
    if (i < 128 * 128) {
        int n = i >> 7, k = i & 127;
        W1t[i] = f2bf(W1[k * 128 + n]);
    }
    int j = i - 128 * 128;
    if (j >= 0 && j < 64 * 128) {
        int n = j >> 7, k = j & 127;
        W2t[j] = f2bf(W2[k * 64 + n]);
    }
}

// ---------- MFMA GEMM: C[r][:] = bf16( dinv[r] * (A[r][:] @ B) ), K=128 ----------
template<int NC, bool ABF16>
__global__ __launch_bounds__(256) void k_gemm(const void* __restrict__ Av,
        const unsigned short* __restrict__ Wt, const float* __restrict__ dinv,
        unsigned short* __restrict__ C, int M) {
    __shared__ unsigned short sA[64][136];
    __shared__ unsigned short sW[NC][136];
    const int tid  = threadIdx.x;
    const int lane = tid & 63;
    const int wave = tid >> 6;
    const int row0 = blockIdx.x * 64;

    if (ABF16) {
        const uint4* A = (const uint4*)Av;
#pragma unroll
        for (int p = 0; p < 4; ++p) {
            int c = tid + p * 256;
            int row = c >> 4, cc = c & 15;
            uint4 v = make_uint4(0u, 0u, 0u, 0u);
            if (row0 + row < M) v = A[(size_t)(row0 + row) * 16 + cc];
            *(uint4*)&sA[row][cc * 8] = v;
        }
    } else {
        const float* A = (const float*)Av;
#pragma unroll
        for (int p = 0; p < 8; ++p) {
            int c = tid + p * 256;
            int row = c >> 5, c4 = (c & 31) * 4;
            float4 v = make_float4(0.f, 0.f, 0.f, 0.f);
            if (row0 + row < M) v = *(const float4*)&A[(size_t)(row0 + row) * 128 + c4];
            ushort4 o;
            o.x = f2bf(v.x); o.y = f2bf(v.y); o.z = f2bf(v.z); o.w = f2bf(v.w);
            *(ushort4*)&sA[row][c4] = o;
        }
    }
    {
        const uint4* W4 = (const uint4*)Wt;
#pragma unroll
        for (int p = 0; p < NC / 16; ++p) {
            int c = tid + p * 256;
            int n = c >> 4, cc = c & 15;
            *(uint4*)&sW[n][cc * 8] = W4[c];
        }
    }
    __syncthreads();

    constexpr int CT = NC / 64;
    const int colbase = wave * (NC / 4);
    const int frow = lane & 15;
    const int fk   = (lane >> 4) * 8;

    f32x4 acc[4][CT];
#pragma unroll
    for (int rt = 0; rt < 4; ++rt)
#pragma unroll
        for (int ct = 0; ct < CT; ++ct) acc[rt][ct] = (f32x4){0.f, 0.f, 0.f, 0.f};

#pragma unroll
    for (int kk = 0; kk < 128; kk += 32) {
        bf16x8 a[4], b[CT];
#pragma unroll
        for (int rt = 0; rt < 4; ++rt)
            a[rt] = *(const bf16x8*)&sA[rt * 16 + frow][kk + fk];
#pragma unroll
        for (int ct = 0; ct < CT; ++ct)
            b[ct] = *(const bf16x8*)&sW[colbase + ct * 16 + frow][kk + fk];
#pragma unroll
        for (int rt = 0; rt < 4; ++rt)
#pragma unroll
            for (int ct = 0; ct < CT; ++ct)
                acc[rt][ct] = __builtin_amdgcn_mfma_f32_16x16x32_bf16(
                    a[rt], b[ct], acc[rt][ct], 0, 0, 0);
    }

    const int crow = (lane >> 4) * 4;
#pragma unroll
    for (int rt = 0; rt < 4; ++rt) {
        int grow = row0 + rt * 16 + crow;
#pragma unroll
        for (int r = 0; r < 4; ++r) {
            if (grow + r < M) {
                float s = dinv[grow + r];
#pragma unroll
                for (int ct = 0; ct < CT; ++ct) {
                    int gcol = colbase + ct * 16 + (lane & 15);
                    C[(size_t)(grow + r) * NC + gcol] = f2bf(acc[rt][ct][r] * s);
                }
            }
        }
    }
}

// ---------- gather D=128 bf16: wave/node, half-wave row slices, 4-deep MLP ----------
template<bool ELU>
__global__ __launch_bounds__(256) void k_gather128(const unsigned* __restrict__ H,
        const int* __restrict__ row_ptr, const int* __restrict__ col,
        const float* __restrict__ dinv, const float* __restrict__ bias,
        unsigned* __restrict__ outbf, int N) {
    const int wave = threadIdx.x >> 6, lane = threadIdx.x & 63;
    const int n = blockIdx.x * 4 + wave;
    if (n >= N) return;
    const int beg = row_ptr[n], end = row_ptr[n + 1];
    const int half = lane >> 5;
    const int s = lane & 31;                    // bf16 cols 4s..4s+3
    float a0 = 0.f, a1 = 0.f, a2 = 0.f, a3 = 0.f;

    if (half == 0) {                            // self row
        uint2 v = *(const uint2*)&H[(size_t)n * 64 + 2 * s];
        a0 += bflo(v.x); a1 += bfhi(v.x); a2 += bflo(v.y); a3 += bfhi(v.y);
    }
    int j = beg + half;
    for (; j + 6 < end; j += 8) {               // 4 neighbors in flight per half
        int c0 = col[j], c1 = col[j + 2], c2 = col[j + 4], c3 = col[j + 6];
        uint2 v0 = *(const uint2*)&H[(size_t)c0 * 64 + 2 * s];
        uint2 v1 = *(const uint2*)&H[(size_t)c1 * 64 + 2 * s];
        uint2 v2 = *(const uint2*)&H[(size_t)c2 * 64 + 2 * s];
        uint2 v3 = *(const uint2*)&H[(size_t)c3 * 64 + 2 * s];
        a0 += bflo(v0.x); a1 += bfhi(v0.x); a2 += bflo(v0.y); a3 += bfhi(v0.y);
        a0 += bflo(v1.x); a1 += bfhi(v1.x); a2 += bflo(v1.y); a3 += bfhi(v1.y);
        a0 += bflo(v2.x); a1 += bfhi(v2.x); a2 += bflo(v2.y); a3 += bfhi(v2.y);
        a0 += bflo(v3.x); a1 += bfhi(v3.x); a2 += bflo(v3.y); a3 += bfhi(v3.y);
    }
    for (; j < end; j += 2) {
        int c0 = col[j];
        uint2 v = *(const uint2*)&H[(size_t)c0 * 64 + 2 * s];
        a0 += bflo(v.x); a1 += bfhi(v.x); a2 += bflo(v.y); a3 += bfhi(v.y);
    }

    a0 += __shfl_xor(a0, 32); a1 += __shfl_xor(a1, 32);
    a2 += __shfl_xor(a2, 32); a3 += __shfl_xor(a3, 32);
    if (half == 0) {
        float sc = dinv[n];
        float4 b = *(const float4*)&bias[4 * s];
        float o0 = fmaf(a0, sc, b.x), o1 = fmaf(a1, sc, b.y);
        float o2 = fmaf(a2, sc, b.z), o3 = fmaf(a3, sc, b.w);
        if (ELU) {
            o0 = o0 > 0.f ? o0 : expm1f(o0);
            o1 = o1 > 0.f ? o1 : expm1f(o1);
            o2 = o2 > 0.f ? o2 : expm1f(o2);
            o3 = o3 > 0.f ? o3 : expm1f(o3);
        }
        uint2 o;
        o.x = (unsigned)f2bf(o0) | ((unsigned)f2bf(o1) << 16);
        o.y = (unsigned)f2bf(o2) | ((unsigned)f2bf(o3) << 16);
        *(uint2*)&outbf[(size_t)n * 64 + 2 * s] = o;
    }
}

// ---------- gather D=64 bf16 in, f32 out: quarter-wave slices, 2-deep MLP ----------
__global__ __launch_bounds__(256) void k_gather64(const unsigned* __restrict__ H,
        const int* __restrict__ row_ptr, const int* __restrict__ col,
        const float* __restrict__ dinv, const float* __restrict__ bias,
        float* __restrict__ out, int N) {
    const int wave = threadIdx.x >> 6, lane = threadIdx.x & 63;
    const int n = blockIdx.x * 4 + wave;
    if (n >= N) return;
    const int beg = row_ptr[n], end = row_ptr[n + 1];
    const int q = lane >> 4;
    const int s = lane & 15;                    // bf16 cols 4s..4s+3
    float a0 = 0.f, a1 = 0.f, a2 = 0.f, a3 = 0.f;

    if (q == 0) {                               // self row
        uint2 v = *(const uint2*)&H[(size_t)n * 32 + 2 * s];
        a0 += bflo(v.x); a1 += bfhi(v.x); a2 += bflo(v.y); a3 += bfhi(v.y);
    }
    int j = beg + q;
    for (; j + 4 < end; j += 8) {               // 2 neighbors in flight per quarter
        int c0 = col[j], c1 = col[j + 4];
        uint2 v0 = *(const uint2*)&H[(size_t)c0 * 32 + 2 * s];
        uint2 v1 = *(const uint2*)&H[(size_t)c1 * 32 + 2 * s];
        a0 += bflo(v0.x); a1 += bfhi(v0.x); a2 += bflo(v0.y); a3 += bfhi(v0.y);
        a0 += bflo(v1.x); a1 += bfhi(v1.x); a2 += bflo(v1.y); a3 += bfhi(v1.y);
    }
    for (; j < end; j += 4) {
        int c0 = col[j];
        uint2 v = *(const uint2*)&H[(size_t)c0 * 32 + 2 * s];
        a0 += bflo(v.x); a1 += bfhi(v.x); a2 += bflo(v.y); a3 += bfhi(v.y);
    }

    a0 += __shfl_xor(a0, 16); a1 += __shfl_xor(a1, 16);
    a2 += __shfl_xor(a2, 16); a3 += __shfl_xor(a3, 16);
    a0 += __shfl_xor(a0, 32); a1 += __shfl_xor(a1, 32);
    a2 += __shfl_xor(a2, 32); a3 += __shfl_xor(a3, 32);
    if (q == 0) {
        float sc = dinv[n];
        float4 b = *(const float4*)&bias[4 * s];
        float4 o;
        o.x = fmaf(a0, sc, b.x); o.y = fmaf(a1, sc, b.y);
        o.z = fmaf(a2, sc, b.z); o.w = fmaf(a3, sc, b.w);
        *(float4*)&out[(size_t)n * 64 + 4 * s] = o;
    }
}

extern "C" void kernel_launch(void* const* d_in, const int* in_sizes, int n_in,
                              void* d_out, int out_size, void* d_ws, size_t ws_size,
                              hipStream_t stream) {
    const float* x  = (const float*)d_in[0];
    const int*   ei = (const int*)d_in[1];
    const float* W1 = (const float*)d_in[2];
    const float* b1 = (const float*)d_in[3];
    const float* W2 = (const float*)d_in[4];
    const float* b2 = (const float*)d_in[5];
    float* out = (float*)d_out;

    const int N = in_sizes[0] / 128;   // 100000
    const int E = in_sizes[1] / 2;     // 800000
    const int* src = ei;
    const int* dst = ei + E;
    const int NB = (N + 255) / 256;    // 391 (<512)
    const int NPAD = (N + 63) & ~63;

    unsigned off = 0;
    int* deg_cursor = (int*)d_ws + off;            off += NPAD + 64;
    int* row_ptr    = (int*)d_ws + off;            off += NPAD + 64;
    int* part       = (int*)d_ws + off;            off += 512;
    int* col        = (int*)d_ws + off;            off += (unsigned)((E + 63) & ~63);
    float* dinv     = (float*)d_ws + off;          off += NPAD + 64;
    unsigned short* W1t = (unsigned short*)((int*)d_ws + off); off += 8192;
    unsigned short* W2t = (unsigned short*)((int*)d_ws + off); off += 4096;
    unsigned* H     = (unsigned*)((int*)d_ws + off); off += (unsigned)N * 64 + 64;
    unsigned* act   = (unsigned*)((int*)d_ws + off);

    // CSR build + weight prep
    hipMemsetAsync(deg_cursor, 0, (size_t)N * sizeof(int), stream);
    k_count<<<(E + 255) / 256, 256, 0, stream>>>(dst, deg_cursor, E);
    k_part<<<NB, 256, 0, stream>>>(deg_cursor, part, N);
    k_scanpart<<<1, 512, 0, stream>>>(part, NB);
    k_finalize<<<NB, 256, 0, stream>>>(deg_cursor, part, row_ptr, dinv, N);
    k_fill<<<(E + 255) / 256, 256, 0, stream>>>(src, dst, deg_cursor, col, E);
    k_prep_w<<<96, 256, 0, stream>>>(W1, W2, W1t, W2t);

    // Layer 1
    k_gemm<128, false><<<(N + 63) / 64, 256, 0, stream>>>(x, W1t, dinv,
                                                          (unsigned short*)H, N);
    k_gather128<true><<<(N + 3) / 4, 256, 0, stream>>>(H, row_ptr, col, dinv, b1, act, N);

    // Layer 2
    k_gemm<64, true><<<(N + 63) / 64, 256, 0, stream>>>(act, W2t, dinv,
                                                        (unsigned short*)H, N);
    k_gather64<<<(N + 3) / 4, 256, 0, stream>>>(H, row_ptr, col, dinv, b2, out, N);
}

// Round 5
// 166.757 us; speedup vs baseline: 13.0810x; 1.3964x over previous
//
#include <hip/hip_runtime.h>

// WalletGNN: 2-layer GCN, N=100000, E=800000, 128 -> 128 -> 64, fp32 in/out.
// R5: CSR build rewritten as atomic-free (global) counting sort:
//     LDS bucket histograms (dst>>8) -> hierarchical scan -> LDS-cursor
//     partition scatter -> per-bucket (256 dst) LDS CSR finalize.
//     GEMMs (MFMA bf16) and MLP-unrolled gathers unchanged from R4.

typedef __attribute__((ext_vector_type(8))) short bf16x8;
typedef __attribute__((ext_vector_type(4))) float f32x4;

static __device__ __forceinline__ unsigned short f2bf(float f) {
    unsigned u = __builtin_bit_cast(unsigned, f);
    u += 0x7fffu + ((u >> 16) & 1u);
    return (unsigned short)(u >> 16);
}
static __device__ __forceinline__ float bflo(unsigned u) {
    return __builtin_bit_cast(float, u << 16);
}
static __device__ __forceinline__ float bfhi(unsigned u) {
    return __builtin_bit_cast(float, u & 0xffff0000u);
}

#define CHUNK 4096              // edges per partition block
#define NBUCKP 512              // padded bucket count (dst>>8 < 391)

// ---------- A1: per-block bucket histogram, bucket-major output ----------
__global__ __launch_bounds__(256) void k_hist(const int* __restrict__ dst,
        int* __restrict__ ghist, int E, int nblk) {
    __shared__ int h[NBUCKP];
    const int tid = threadIdx.x, b = blockIdx.x;
    h[tid] = 0; h[tid + 256] = 0;
    __syncthreads();
    const int base = b * CHUNK;
#pragma unroll
    for (int i = 0; i < CHUNK / 256; ++i) {
        int e = base + i * 256 + tid;
        if (e < E) atomicAdd(&h[dst[e] >> 8], 1);
    }
    __syncthreads();
    ghist[tid * nblk + b] = h[tid];
    ghist[(tid + 256) * nblk + b] = h[tid + 256];
}

// ---------- generic hierarchical scan helpers ----------
__global__ __launch_bounds__(256) void k_part(const int* __restrict__ v,
                                              int* __restrict__ part, int L) {
    __shared__ int s[256];
    int tid = threadIdx.x;
    int i = blockIdx.x * 256 + tid;
    s[tid] = (i < L) ? v[i] : 0;
    __syncthreads();
    for (int o = 128; o > 0; o >>= 1) {
        if (tid < o) s[tid] += s[tid + o];
        __syncthreads();
    }
    if (tid == 0) part[blockIdx.x] = s[0];
}

__global__ __launch_bounds__(512) void k_scanpart(int* __restrict__ part, int nb) {
    __shared__ int s[512];
    int tid = threadIdx.x;
    int v = (tid < nb) ? part[tid] : 0;
    s[tid] = v;
    __syncthreads();
    for (int off = 1; off < 512; off <<= 1) {
        int t = (tid >= off) ? s[tid - off] : 0;
        __syncthreads();
        s[tid] += t;
        __syncthreads();
    }
    if (tid < nb) part[tid] = s[tid] - v;   // exclusive
}

// in-place exclusive scan: v[i] = part[blk] + excl_scan_within_block
__global__ __launch_bounds__(256) void k_scan_apply(int* __restrict__ v,
        const int* __restrict__ part, int L) {
    __shared__ int s[256];
    int tid = threadIdx.x;
    int i = blockIdx.x * 256 + tid;
    int x = (i < L) ? v[i] : 0;
    s[tid] = x;
    __syncthreads();
    for (int off = 1; off < 256; off <<= 1) {
        int t = (tid >= off) ? s[tid - off] : 0;
        __syncthreads();
        s[tid] += t;
        __syncthreads();
    }
    if (i < L) v[i] = part[blockIdx.x] + s[tid] - x;
}

// ---------- A3: partition scatter via LDS cursors (no global atomics) ----------
__global__ __launch_bounds__(256) void k_scatter_part(const int* __restrict__ src,
        const int* __restrict__ dst, const int* __restrict__ S /*scanned ghist*/,
        uint2* __restrict__ eb, int E, int nblk) {
    __shared__ int cur[NBUCKP];
    const int tid = threadIdx.x, b = blockIdx.x;
    cur[tid] = S[tid * nblk + b];
    cur[tid + 256] = S[(tid + 256) * nblk + b];
    __syncthreads();
    const int base = b * CHUNK;
#pragma unroll
    for (int i = 0; i < CHUNK / 256; ++i) {
        int e = base + i * 256 + tid;
        if (e < E) {
            int s = src[e], d = dst[e];
            int pos = atomicAdd(&cur[d >> 8], 1);
            eb[pos] = make_uint2((unsigned)s, (unsigned)d);
        }
    }
}

// ---------- B: per-bucket CSR finalize (256 dst values per block) ----------
__global__ __launch_bounds__(256) void k_bucket_csr(const uint2* __restrict__ eb,
        const int* __restrict__ S, int* __restrict__ row_ptr,
        float* __restrict__ dinv, int* __restrict__ col, int E, int nblk, int N) {
    __shared__ int h[256], sc[256], cur[256];
    const int tid = threadIdx.x, k = blockIdx.x;
    const int bstart = S[k * nblk];
    const int bend   = S[(k + 1) * nblk];
    h[tid] = 0;
    __syncthreads();
    for (int e = bstart + tid; e < bend; e += 256)
        atomicAdd(&h[eb[e].y & 255], 1);
    __syncthreads();
    int v = h[tid];
    sc[tid] = v;
    __syncthreads();
    for (int off = 1; off < 256; off <<= 1) {
        int t = (tid >= off) ? sc[tid - off] : 0;
        __syncthreads();
        sc[tid] += t;
        __syncthreads();
    }
    int excl = sc[tid] - v;
    int n = k * 256 + tid;
    if (n < N) {
        row_ptr[n] = bstart + excl;
        dinv[n] = rsqrtf((float)v + 1.0f);    // +1 self-loop
        if (n == N - 1) row_ptr[N] = bstart + excl + v;
    }
    cur[tid] = excl;
    __syncthreads();
    for (int e = bstart + tid; e < bend; e += 256) {
        uint2 ed = eb[e];
        int pos = bstart + atomicAdd(&cur[ed.y & 255], 1);
        col[pos] = (int)ed.x;
    }
}

// ---------- W -> W^T bf16 ----------
__global__ __launch_bounds__(256) void k_prep_w(const float* __restrict__ W1,
        const float* __restrict__ W2, unsigned short* __restrict__ W1t,
        unsigned short* __restrict__ W2t) {
    int i = blockIdx.x * 256 + threadIdx.x;
    if (i < 128 * 128) {
        int n = i >> 7, k = i & 127;
        W1t[i] = f2bf(W1[k * 128 + n]);
    }
    int j = i - 128 * 128;
    if (j >= 0 && j < 64 * 128) {
        int n = j >> 7, k = j & 127;
        W2t[j] = f2bf(W2[k * 64 + n]);
    }
}

// ---------- MFMA GEMM: C[r][:] = bf16( dinv[r] * (A[r][:] @ B) ), K=128 ----------
template<int NC, bool ABF16>
__global__ __launch_bounds__(256) void k_gemm(const void* __restrict__ Av,
        const unsigned short* __restrict__ Wt, const float* __restrict__ dinv,
        unsigned short* __restrict__ C, int M) {
    __shared__ unsigned short sA[64][136];
    __shared__ unsigned short sW[NC][136];
    const int tid  = threadIdx.x;
    const int lane = tid & 63;
    const int wave = tid >> 6;
    const int row0 = blockIdx.x * 64;

    if (ABF16) {
        const uint4* A = (const uint4*)Av;
#pragma unroll
        for (int p = 0; p < 4; ++p) {
            int c = tid + p * 256;
            int row = c >> 4, cc = c & 15;
            uint4 v = make_uint4(0u, 0u, 0u, 0u);
            if (row0 + row < M) v = A[(size_t)(row0 + row) * 16 + cc];
            *(uint4*)&sA[row][cc * 8] = v;
        }
    } else {
        const float* A = (const float*)Av;
#pragma unroll
        for (int p = 0; p < 8; ++p) {
            int c = tid + p * 256;
            int row = c >> 5, c4 = (c & 31) * 4;
            float4 v = make_float4(0.f, 0.f, 0.f, 0.f);
            if (row0 + row < M) v = *(const float4*)&A[(size_t)(row0 + row) * 128 + c4];
            ushort4 o;
            o.x = f2bf(v.x); o.y = f2bf(v.y); o.z = f2bf(v.z); o.w = f2bf(v.w);
            *(ushort4*)&sA[row][c4] = o;
        }
    }
    {
        const uint4* W4 = (const uint4*)Wt;
#pragma unroll
        for (int p = 0; p < NC / 16; ++p) {
            int c = tid + p * 256;
            int n = c >> 4, cc = c & 15;
            *(uint4*)&sW[n][cc * 8] = W4[c];
        }
    }
    __syncthreads();

    constexpr int CT = NC / 64;
    const int colbase = wave * (NC / 4);
    const int frow = lane & 15;
    const int fk   = (lane >> 4) * 8;

    f32x4 acc[4][CT];
#pragma unroll
    for (int rt = 0; rt < 4; ++rt)
#pragma unroll
        for (int ct = 0; ct < CT; ++ct) acc[rt][ct] = (f32x4){0.f, 0.f, 0.f, 0.f};

#pragma unroll
    for (int kk = 0; kk < 128; kk += 32) {
        bf16x8 a[4], b[CT];
#pragma unroll
        for (int rt = 0; rt < 4; ++rt)
            a[rt] = *(const bf16x8*)&sA[rt * 16 + frow][kk + fk];
#pragma unroll
        for (int ct = 0; ct < CT; ++ct)
            b[ct] = *(const bf16x8*)&sW[colbase + ct * 16 + frow][kk + fk];
#pragma unroll
        for (int rt = 0; rt < 4; ++rt)
#pragma unroll
            for (int ct = 0; ct < CT; ++ct)
                acc[rt][ct] = __builtin_amdgcn_mfma_f32_16x16x32_bf16(
                    a[rt], b[ct], acc[rt][ct], 0, 0, 0);
    }

    const int crow = (lane >> 4) * 4;
#pragma unroll
    for (int rt = 0; rt < 4; ++rt) {
        int grow = row0 + rt * 16 + crow;
#pragma unroll
        for (int r = 0; r < 4; ++r) {
            if (grow + r < M) {
                float s = dinv[grow + r];
#pragma unroll
                for (int ct = 0; ct < CT; ++ct) {
                    int gcol = colbase + ct * 16 + (lane & 15);
                    C[(size_t)(grow + r) * NC + gcol] = f2bf(acc[rt][ct][r] * s);
                }
            }
        }
    }
}

// ---------- gather D=128 bf16: wave/node, half-wave row slices, 4-deep MLP ----------
template<bool ELU>
__global__ __launch_bounds__(256) void k_gather128(const unsigned* __restrict__ H,
        const int* __restrict__ row_ptr, const int* __restrict__ col,
        const float* __restrict__ dinv, const float* __restrict__ bias,
        unsigned* __restrict__ outbf, int N) {
    const int wave = threadIdx.x >> 6, lane = threadIdx.x & 63;
    const int n = blockIdx.x * 4 + wave;
    if (n >= N) return;
    const int beg = row_ptr[n], end = row_ptr[n + 1];
    const int half = lane >> 5;
    const int s = lane & 31;
    float a0 = 0.f, a1 = 0.f, a2 = 0.f, a3 = 0.f;

    if (half == 0) {
        uint2 v = *(const uint2*)&H[(size_t)n * 64 + 2 * s];
        a0 += bflo(v.x); a1 += bfhi(v.x); a2 += bflo(v.y); a3 += bfhi(v.y);
    }
    int j = beg + half;
    for (; j + 6 < end; j += 8) {
        int c0 = col[j], c1 = col[j + 2], c2 = col[j + 4], c3 = col[j + 6];
        uint2 v0 = *(const uint2*)&H[(size_t)c0 * 64 + 2 * s];
        uint2 v1 = *(const uint2*)&H[(size_t)c1 * 64 + 2 * s];
        uint2 v2 = *(const uint2*)&H[(size_t)c2 * 64 + 2 * s];
        uint2 v3 = *(const uint2*)&H[(size_t)c3 * 64 + 2 * s];
        a0 += bflo(v0.x); a1 += bfhi(v0.x); a2 += bflo(v0.y); a3 += bfhi(v0.y);
        a0 += bflo(v1.x); a1 += bfhi(v1.x); a2 += bflo(v1.y); a3 += bfhi(v1.y);
        a0 += bflo(v2.x); a1 += bfhi(v2.x); a2 += bflo(v2.y); a3 += bfhi(v2.y);
        a0 += bflo(v3.x); a1 += bfhi(v3.x); a2 += bflo(v3.y); a3 += bfhi(v3.y);
    }
    for (; j < end; j += 2) {
        int c0 = col[j];
        uint2 v = *(const uint2*)&H[(size_t)c0 * 64 + 2 * s];
        a0 += bflo(v.x); a1 += bfhi(v.x); a2 += bflo(v.y); a3 += bfhi(v.y);
    }

    a0 += __shfl_xor(a0, 32); a1 += __shfl_xor(a1, 32);
    a2 += __shfl_xor(a2, 32); a3 += __shfl_xor(a3, 32);
    if (half == 0) {
        float sc = dinv[n];
        float4 b = *(const float4*)&bias[4 * s];
        float o0 = fmaf(a0, sc, b.x), o1 = fmaf(a1, sc, b.y);
        float o2 = fmaf(a2, sc, b.z), o3 = fmaf(a3, sc, b.w);
        if (ELU) {
            o0 = o0 > 0.f ? o0 : expm1f(o0);
            o1 = o1 > 0.f ? o1 : expm1f(o1);
            o2 = o2 > 0.f ? o2 : expm1f(o2);
            o3 = o3 > 0.f ? o3 : expm1f(o3);
        }
        uint2 o;
        o.x = (unsigned)f2bf(o0) | ((unsigned)f2bf(o1) << 16);
        o.y = (unsigned)f2bf(o2) | ((unsigned)f2bf(o3) << 16);
        *(uint2*)&outbf[(size_t)n * 64 + 2 * s] = o;
    }
}

// ---------- gather D=64 bf16 in, f32 out: quarter-wave slices, 2-deep MLP ----------
__global__ __launch_bounds__(256) void k_gather64(const unsigned* __restrict__ H,
        const int* __restrict__ row_ptr, const int* __restrict__ col,
        const float* __restrict__ dinv, const float* __restrict__ bias,
        float* __restrict__ out, int N) {
    const int wave = threadIdx.x >> 6, lane = threadIdx.x & 63;
    const int n = blockIdx.x * 4 + wave;
    if (n >= N) return;
    const int beg = row_ptr[n], end = row_ptr[n + 1];
    const int q = lane >> 4;
    const int s = lane & 15;
    float a0 = 0.f, a1 = 0.f, a2 = 0.f, a3 = 0.f;

    if (q == 0) {
        uint2 v = *(const uint2*)&H[(size_t)n * 32 + 2 * s];
        a0 += bflo(v.x); a1 += bfhi(v.x); a2 += bflo(v.y); a3 += bfhi(v.y);
    }
    int j = beg + q;
    for (; j + 4 < end; j += 8) {
        int c0 = col[j], c1 = col[j + 4];
        uint2 v0 = *(const uint2*)&H[(size_t)c0 * 32 + 2 * s];
        uint2 v1 = *(const uint2*)&H[(size_t)c1 * 32 + 2 * s];
        a0 += bflo(v0.x); a1 += bfhi(v0.x); a2 += bflo(v0.y); a3 += bfhi(v0.y);
        a0 += bflo(v1.x); a1 += bfhi(v1.x); a2 += bflo(v1.y); a3 += bfhi(v1.y);
    }
    for (; j < end; j += 4) {
        int c0 = col[j];
        uint2 v = *(const uint2*)&H[(size_t)c0 * 32 + 2 * s];
        a0 += bflo(v.x); a1 += bfhi(v.x); a2 += bflo(v.y); a3 += bfhi(v.y);
    }

    a0 += __shfl_xor(a0, 16); a1 += __shfl_xor(a1, 16);
    a2 += __shfl_xor(a2, 16); a3 += __shfl_xor(a3, 16);
    a0 += __shfl_xor(a0, 32); a1 += __shfl_xor(a1, 32);
    a2 += __shfl_xor(a2, 32); a3 += __shfl_xor(a3, 32);
    if (q == 0) {
        float sc = dinv[n];
        float4 b = *(const float4*)&bias[4 * s];
        float4 o;
        o.x = fmaf(a0, sc, b.x); o.y = fmaf(a1, sc, b.y);
        o.z = fmaf(a2, sc, b.z); o.w = fmaf(a3, sc, b.w);
        *(float4*)&out[(size_t)n * 64 + 4 * s] = o;
    }
}

extern "C" void kernel_launch(void* const* d_in, const int* in_sizes, int n_in,
                              void* d_out, int out_size, void* d_ws, size_t ws_size,
                              hipStream_t stream) {
    const float* x  = (const float*)d_in[0];
    const int*   ei = (const int*)d_in[1];
    const float* W1 = (const float*)d_in[2];
    const float* b1 = (const float*)d_in[3];
    const float* W2 = (const float*)d_in[4];
    const float* b2 = (const float*)d_in[5];
    float* out = (float*)d_out;

    const int N = in_sizes[0] / 128;   // 100000
    const int E = in_sizes[1] / 2;     // 800000
    const int* src = ei;
    const int* dst = ei + E;
    const int NPAD = (N + 63) & ~63;

    const int NBLK_A = (E + CHUNK - 1) / CHUNK;        // 196
    const int L      = NBUCKP * NBLK_A;                // 100352
    const int NBLK_S = (L + 255) / 256;                // 392  (<=512)
    const int NBUCK  = (N + 255) / 256;                // 391

    // workspace layout (4-byte units)
    unsigned off = 0;
    int* row_ptr    = (int*)d_ws + off;            off += NPAD + 64;
    float* dinv     = (float*)((int*)d_ws + off);  off += NPAD + 64;
    int* ghist      = (int*)d_ws + off;            off += (unsigned)((L + 63) & ~63);
    int* part       = (int*)d_ws + off;            off += 512;
    uint2* eb       = (uint2*)((int*)d_ws + off);  off += (unsigned)(2 * ((E + 63) & ~63));
    int* col        = (int*)d_ws + off;            off += (unsigned)((E + 63) & ~63);
    unsigned short* W1t = (unsigned short*)((int*)d_ws + off); off += 8192;
    unsigned short* W2t = (unsigned short*)((int*)d_ws + off); off += 4096;
    unsigned* H     = (unsigned*)((int*)d_ws + off); off += (unsigned)N * 64 + 64;
    unsigned* act   = (unsigned*)((int*)d_ws + off);

    // CSR build (no global atomics)
    k_hist<<<NBLK_A, 256, 0, stream>>>(dst, ghist, E, NBLK_A);
    k_part<<<NBLK_S, 256, 0, stream>>>(ghist, part, L);
    k_scanpart<<<1, 512, 0, stream>>>(part, NBLK_S);
    k_scan_apply<<<NBLK_S, 256, 0, stream>>>(ghist, part, L);
    k_scatter_part<<<NBLK_A, 256, 0, stream>>>(src, dst, ghist, eb, E, NBLK_A);
    k_bucket_csr<<<NBUCK, 256, 0, stream>>>(eb, ghist, row_ptr, dinv, col, E, NBLK_A, N);
    k_prep_w<<<96, 256, 0, stream>>>(W1, W2, W1t, W2t);

    // Layer 1
    k_gemm<128, false><<<(N + 63) / 64, 256, 0, stream>>>(x, W1t, dinv,
                                                          (unsigned short*)H, N);
    k_gather128<true><<<(N + 3) / 4, 256, 0, stream>>>(H, row_ptr, col, dinv, b1, act, N);

    // Layer 2
    k_gemm<64, true><<<(N + 63) / 64, 256, 0, stream>>>(act, W2t, dinv,
                                                        (unsigned short*)H, N);
    k_gather64<<<(N + 3) / 4, 256, 0, stream>>>(H, row_ptr, col, dinv, b2, out, N);
}

// Round 6
// 155.094 us; speedup vs baseline: 14.0646x; 1.0752x over previous
//
#include <hip/hip_runtime.h>

// WalletGNN: 2-layer GCN, N=100000, E=800000, 128 -> 128 -> 64, fp32 in/out.
// R6: gather tails de-serialized (predicated clamped-index load groups,
//     zero-weighted via fmaf); gather64 main loop 4-deep; partition-scatter
//     element packed to uint32 (dst&255 << 24 | src).

typedef __attribute__((ext_vector_type(8))) short bf16x8;
typedef __attribute__((ext_vector_type(4))) float f32x4;

static __device__ __forceinline__ unsigned short f2bf(float f) {
    unsigned u = __builtin_bit_cast(unsigned, f);
    u += 0x7fffu + ((u >> 16) & 1u);
    return (unsigned short)(u >> 16);
}
static __device__ __forceinline__ float bflo(unsigned u) {
    return __builtin_bit_cast(float, u << 16);
}
static __device__ __forceinline__ float bfhi(unsigned u) {
    return __builtin_bit_cast(float, u & 0xffff0000u);
}

#define CHUNK 4096              // edges per partition block
#define NBUCKP 512              // padded bucket count (dst>>8 < 391)

// ---------- A1: per-block bucket histogram, bucket-major output ----------
__global__ __launch_bounds__(256) void k_hist(const int* __restrict__ dst,
        int* __restrict__ ghist, int E, int nblk) {
    __shared__ int h[NBUCKP];
    const int tid = threadIdx.x, b = blockIdx.x;
    h[tid] = 0; h[tid + 256] = 0;
    __syncthreads();
    const int base = b * CHUNK;
#pragma unroll
    for (int i = 0; i < CHUNK / 256; ++i) {
        int e = base + i * 256 + tid;
        if (e < E) atomicAdd(&h[dst[e] >> 8], 1);
    }
    __syncthreads();
    ghist[tid * nblk + b] = h[tid];
    ghist[(tid + 256) * nblk + b] = h[tid + 256];
}

// ---------- hierarchical scan helpers ----------
__global__ __launch_bounds__(256) void k_part(const int* __restrict__ v,
                                              int* __restrict__ part, int L) {
    __shared__ int s[256];
    int tid = threadIdx.x;
    int i = blockIdx.x * 256 + tid;
    s[tid] = (i < L) ? v[i] : 0;
    __syncthreads();
    for (int o = 128; o > 0; o >>= 1) {
        if (tid < o) s[tid] += s[tid + o];
        __syncthreads();
    }
    if (tid == 0) part[blockIdx.x] = s[0];
}

__global__ __launch_bounds__(512) void k_scanpart(int* __restrict__ part, int nb) {
    __shared__ int s[512];
    int tid = threadIdx.x;
    int v = (tid < nb) ? part[tid] : 0;
    s[tid] = v;
    __syncthreads();
    for (int off = 1; off < 512; off <<= 1) {
        int t = (tid >= off) ? s[tid - off] : 0;
        __syncthreads();
        s[tid] += t;
        __syncthreads();
    }
    if (tid < nb) part[tid] = s[tid] - v;   // exclusive
}

__global__ __launch_bounds__(256) void k_scan_apply(int* __restrict__ v,
        const int* __restrict__ part, int L) {
    __shared__ int s[256];
    int tid = threadIdx.x;
    int i = blockIdx.x * 256 + tid;
    int x = (i < L) ? v[i] : 0;
    s[tid] = x;
    __syncthreads();
    for (int off = 1; off < 256; off <<= 1) {
        int t = (tid >= off) ? s[tid - off] : 0;
        __syncthreads();
        s[tid] += t;
        __syncthreads();
    }
    if (i < L) v[i] = part[blockIdx.x] + s[tid] - x;
}

// ---------- A3: partition scatter via LDS cursors (packed uint32) ----------
__global__ __launch_bounds__(256) void k_scatter_part(const int* __restrict__ src,
        const int* __restrict__ dst, const int* __restrict__ S,
        unsigned* __restrict__ eb, int E, int nblk) {
    __shared__ int cur[NBUCKP];
    const int tid = threadIdx.x, b = blockIdx.x;
    cur[tid] = S[tid * nblk + b];
    cur[tid + 256] = S[(tid + 256) * nblk + b];
    __syncthreads();
    const int base = b * CHUNK;
#pragma unroll
    for (int i = 0; i < CHUNK / 256; ++i) {
        int e = base + i * 256 + tid;
        if (e < E) {
            int s = src[e], d = dst[e];
            int pos = atomicAdd(&cur[d >> 8], 1);
            eb[pos] = ((unsigned)(d & 255) << 24) | (unsigned)s;
        }
    }
}

// ---------- B: per-bucket CSR finalize (256 dst values per block) ----------
__global__ __launch_bounds__(256) void k_bucket_csr(const unsigned* __restrict__ eb,
        const int* __restrict__ S, int* __restrict__ row_ptr,
        float* __restrict__ dinv, int* __restrict__ col, int E, int nblk, int N) {
    __shared__ int h[256], sc[256], cur[256];
    const int tid = threadIdx.x, k = blockIdx.x;
    const int bstart = S[k * nblk];
    const int bend   = S[(k + 1) * nblk];
    h[tid] = 0;
    __syncthreads();
    for (int e = bstart + tid; e < bend; e += 256)
        atomicAdd(&h[eb[e] >> 24], 1);
    __syncthreads();
    int v = h[tid];
    sc[tid] = v;
    __syncthreads();
    for (int off = 1; off < 256; off <<= 1) {
        int t = (tid >= off) ? sc[tid - off] : 0;
        __syncthreads();
        sc[tid] += t;
        __syncthreads();
    }
    int excl = sc[tid] - v;
    int n = k * 256 + tid;
    if (n < N) {
        row_ptr[n] = bstart + excl;
        dinv[n] = rsqrtf((float)v + 1.0f);    // +1 self-loop
        if (n == N - 1) row_ptr[N] = bstart + excl + v;
    }
    cur[tid] = excl;
    __syncthreads();
    for (int e = bstart + tid; e < bend; e += 256) {
        unsigned ed = eb[e];
        int pos = bstart + atomicAdd(&cur[ed >> 24], 1);
        col[pos] = (int)(ed & 0xFFFFFFu);
    }
}

// ---------- W -> W^T bf16 ----------
__global__ __launch_bounds__(256) void k_prep_w(const float* __restrict__ W1,
        const float* __restrict__ W2, unsigned short* __restrict__ W1t,
        unsigned short* __restrict__ W2t) {
    int i = blockIdx.x * 256 + threadIdx.x;
    if (i < 128 * 128) {
        int n = i >> 7, k = i & 127;
        W1t[i] = f2bf(W1[k * 128 + n]);
    }
    int j = i - 128 * 128;
    if (j >= 0 && j < 64 * 128) {
        int n = j >> 7, k = j & 127;
        W2t[j] = f2bf(W2[k * 64 + n]);
    }
}

// ---------- MFMA GEMM: C[r][:] = bf16( dinv[r] * (A[r][:] @ B) ), K=128 ----------
template<int NC, bool ABF16>
__global__ __launch_bounds__(256) void k_gemm(const void* __restrict__ Av,
        const unsigned short* __restrict__ Wt, const float* __restrict__ dinv,
        unsigned short* __restrict__ C, int M) {
    __shared__ unsigned short sA[64][136];
    __shared__ unsigned short sW[NC][136];
    const int tid  = threadIdx.x;
    const int lane = tid & 63;
    const int wave = tid >> 6;
    const int row0 = blockIdx.x * 64;

    if (ABF16) {
        const uint4* A = (const uint4*)Av;
#pragma unroll
        for (int p = 0; p < 4; ++p) {
            int c = tid + p * 256;
            int row = c >> 4, cc = c & 15;
            uint4 v = make_uint4(0u, 0u, 0u, 0u);
            if (row0 + row < M) v = A[(size_t)(row0 + row) * 16 + cc];
            *(uint4*)&sA[row][cc * 8] = v;
        }
    } else {
        const float* A = (const float*)Av;
#pragma unroll
        for (int p = 0; p < 8; ++p) {
            int c = tid + p * 256;
            int row = c >> 5, c4 = (c & 31) * 4;
            float4 v = make_float4(0.f, 0.f, 0.f, 0.f);
            if (row0 + row < M) v = *(const float4*)&A[(size_t)(row0 + row) * 128 + c4];
            ushort4 o;
            o.x = f2bf(v.x); o.y = f2bf(v.y); o.z = f2bf(v.z); o.w = f2bf(v.w);
            *(ushort4*)&sA[row][c4] = o;
        }
    }
    {
        const uint4* W4 = (const uint4*)Wt;
#pragma unroll
        for (int p = 0; p < NC / 16; ++p) {
            int c = tid + p * 256;
            int n = c >> 4, cc = c & 15;
            *(uint4*)&sW[n][cc * 8] = W4[c];
        }
    }
    __syncthreads();

    constexpr int CT = NC / 64;
    const int colbase = wave * (NC / 4);
    const int frow = lane & 15;
    const int fk   = (lane >> 4) * 8;

    f32x4 acc[4][CT];
#pragma unroll
    for (int rt = 0; rt < 4; ++rt)
#pragma unroll
        for (int ct = 0; ct < CT; ++ct) acc[rt][ct] = (f32x4){0.f, 0.f, 0.f, 0.f};

#pragma unroll
    for (int kk = 0; kk < 128; kk += 32) {
        bf16x8 a[4], b[CT];
#pragma unroll
        for (int rt = 0; rt < 4; ++rt)
            a[rt] = *(const bf16x8*)&sA[rt * 16 + frow][kk + fk];
#pragma unroll
        for (int ct = 0; ct < CT; ++ct)
            b[ct] = *(const bf16x8*)&sW[colbase + ct * 16 + frow][kk + fk];
#pragma unroll
        for (int rt = 0; rt < 4; ++rt)
#pragma unroll
            for (int ct = 0; ct < CT; ++ct)
                acc[rt][ct] = __builtin_amdgcn_mfma_f32_16x16x32_bf16(
                    a[rt], b[ct], acc[rt][ct], 0, 0, 0);
    }

    const int crow = (lane >> 4) * 4;
#pragma unroll
    for (int rt = 0; rt < 4; ++rt) {
        int grow = row0 + rt * 16 + crow;
#pragma unroll
        for (int r = 0; r < 4; ++r) {
            if (grow + r < M) {
                float s = dinv[grow + r];
#pragma unroll
                for (int ct = 0; ct < CT; ++ct) {
                    int gcol = colbase + ct * 16 + (lane & 15);
                    C[(size_t)(grow + r) * NC + gcol] = f2bf(acc[rt][ct][r] * s);
                }
            }
        }
    }
}

// ---------- gather D=128: wave/node, half-wave slices, predicated tail ----------
template<bool ELU>
__global__ __launch_bounds__(256) void k_gather128(const unsigned* __restrict__ H,
        const int* __restrict__ row_ptr, const int* __restrict__ col,
        const float* __restrict__ dinv, const float* __restrict__ bias,
        unsigned* __restrict__ outbf, int N) {
    const int wave = threadIdx.x >> 6, lane = threadIdx.x & 63;
    const int n = blockIdx.x * 4 + wave;
    if (n >= N) return;
    const int beg = row_ptr[n], end = row_ptr[n + 1];
    const int half = lane >> 5;
    const int s = lane & 31;
    float a0 = 0.f, a1 = 0.f, a2 = 0.f, a3 = 0.f;

    if (half == 0) {                            // self row
        uint2 v = *(const uint2*)&H[(size_t)n * 64 + 2 * s];
        a0 += bflo(v.x); a1 += bfhi(v.x); a2 += bflo(v.y); a3 += bfhi(v.y);
    }
    int j = beg + half;
    for (; j + 6 < end; j += 8) {               // 4 neighbors in flight per half
        int c0 = col[j], c1 = col[j + 2], c2 = col[j + 4], c3 = col[j + 6];
        uint2 v0 = *(const uint2*)&H[(size_t)c0 * 64 + 2 * s];
        uint2 v1 = *(const uint2*)&H[(size_t)c1 * 64 + 2 * s];
        uint2 v2 = *(const uint2*)&H[(size_t)c2 * 64 + 2 * s];
        uint2 v3 = *(const uint2*)&H[(size_t)c3 * 64 + 2 * s];
        a0 += bflo(v0.x); a1 += bfhi(v0.x); a2 += bflo(v0.y); a3 += bfhi(v0.y);
        a0 += bflo(v1.x); a1 += bfhi(v1.x); a2 += bflo(v1.y); a3 += bfhi(v1.y);
        a0 += bflo(v2.x); a1 += bfhi(v2.x); a2 += bflo(v2.y); a3 += bfhi(v2.y);
        a0 += bflo(v3.x); a1 += bfhi(v3.x); a2 += bflo(v3.y); a3 += bfhi(v3.y);
    }
    if (j < end) {                              // predicated tail (<=3 items)
        const int e1 = end - 1;
        int j1 = j + 2, j2 = j + 4;
        int c0 = col[j];
        int c1 = col[j1 <= e1 ? j1 : e1];       // clamped: cache-hot row
        int c2 = col[j2 <= e1 ? j2 : e1];
        float w1 = (j1 < end) ? 1.f : 0.f;
        float w2 = (j2 < end) ? 1.f : 0.f;
        uint2 v0 = *(const uint2*)&H[(size_t)c0 * 64 + 2 * s];
        uint2 v1 = *(const uint2*)&H[(size_t)c1 * 64 + 2 * s];
        uint2 v2 = *(const uint2*)&H[(size_t)c2 * 64 + 2 * s];
        a0 += bflo(v0.x); a1 += bfhi(v0.x); a2 += bflo(v0.y); a3 += bfhi(v0.y);
        a0 = fmaf(bflo(v1.x), w1, a0); a1 = fmaf(bfhi(v1.x), w1, a1);
        a2 = fmaf(bflo(v1.y), w1, a2); a3 = fmaf(bfhi(v1.y), w1, a3);
        a0 = fmaf(bflo(v2.x), w2, a0); a1 = fmaf(bfhi(v2.x), w2, a1);
        a2 = fmaf(bflo(v2.y), w2, a2); a3 = fmaf(bfhi(v2.y), w2, a3);
    }

    a0 += __shfl_xor(a0, 32); a1 += __shfl_xor(a1, 32);
    a2 += __shfl_xor(a2, 32); a3 += __shfl_xor(a3, 32);
    if (half == 0) {
        float sc = dinv[n];
        float4 b = *(const float4*)&bias[4 * s];
        float o0 = fmaf(a0, sc, b.x), o1 = fmaf(a1, sc, b.y);
        float o2 = fmaf(a2, sc, b.z), o3 = fmaf(a3, sc, b.w);
        if (ELU) {
            o0 = o0 > 0.f ? o0 : expm1f(o0);
            o1 = o1 > 0.f ? o1 : expm1f(o1);
            o2 = o2 > 0.f ? o2 : expm1f(o2);
            o3 = o3 > 0.f ? o3 : expm1f(o3);
        }
        uint2 o;
        o.x = (unsigned)f2bf(o0) | ((unsigned)f2bf(o1) << 16);
        o.y = (unsigned)f2bf(o2) | ((unsigned)f2bf(o3) << 16);
        *(uint2*)&outbf[(size_t)n * 64 + 2 * s] = o;
    }
}

// ---------- gather D=64: quarter-wave slices, 4-deep + predicated tail ----------
__global__ __launch_bounds__(256) void k_gather64(const unsigned* __restrict__ H,
        const int* __restrict__ row_ptr, const int* __restrict__ col,
        const float* __restrict__ dinv, const float* __restrict__ bias,
        float* __restrict__ out, int N) {
    const int wave = threadIdx.x >> 6, lane = threadIdx.x & 63;
    const int n = blockIdx.x * 4 + wave;
    if (n >= N) return;
    const int beg = row_ptr[n], end = row_ptr[n + 1];
    const int q = lane >> 4;
    const int s = lane & 15;
    float a0 = 0.f, a1 = 0.f, a2 = 0.f, a3 = 0.f;

    if (q == 0) {                               // self row
        uint2 v = *(const uint2*)&H[(size_t)n * 32 + 2 * s];
        a0 += bflo(v.x); a1 += bfhi(v.x); a2 += bflo(v.y); a3 += bfhi(v.y);
    }
    int j = beg + q;
    for (; j + 12 < end; j += 16) {             // 4 neighbors in flight per quarter
        int c0 = col[j], c1 = col[j + 4], c2 = col[j + 8], c3 = col[j + 12];
        uint2 v0 = *(const uint2*)&H[(size_t)c0 * 32 + 2 * s];
        uint2 v1 = *(const uint2*)&H[(size_t)c1 * 32 + 2 * s];
        uint2 v2 = *(const uint2*)&H[(size_t)c2 * 32 + 2 * s];
        uint2 v3 = *(const uint2*)&H[(size_t)c3 * 32 + 2 * s];
        a0 += bflo(v0.x); a1 += bfhi(v0.x); a2 += bflo(v0.y); a3 += bfhi(v0.y);
        a0 += bflo(v1.x); a1 += bfhi(v1.x); a2 += bflo(v1.y); a3 += bfhi(v1.y);
        a0 += bflo(v2.x); a1 += bfhi(v2.x); a2 += bflo(v2.y); a3 += bfhi(v2.y);
        a0 += bflo(v3.x); a1 += bfhi(v3.x); a2 += bflo(v3.y); a3 += bfhi(v3.y);
    }
    if (j < end) {                              // predicated tail (<=3 items)
        const int e1 = end - 1;
        int j1 = j + 4, j2 = j + 8;
        int c0 = col[j];
        int c1 = col[j1 <= e1 ? j1 : e1];
        int c2 = col[j2 <= e1 ? j2 : e1];
        float w1 = (j1 < end) ? 1.f : 0.f;
        float w2 = (j2 < end) ? 1.f : 0.f;
        uint2 v0 = *(const uint2*)&H[(size_t)c0 * 32 + 2 * s];
        uint2 v1 = *(const uint2*)&H[(size_t)c1 * 32 + 2 * s];
        uint2 v2 = *(const uint2*)&H[(size_t)c2 * 32 + 2 * s];
        a0 += bflo(v0.x); a1 += bfhi(v0.x); a2 += bflo(v0.y); a3 += bfhi(v0.y);
        a0 = fmaf(bflo(v1.x), w1, a0); a1 = fmaf(bfhi(v1.x), w1, a1);
        a2 = fmaf(bflo(v1.y), w1, a2); a3 = fmaf(bfhi(v1.y), w1, a3);
        a0 = fmaf(bflo(v2.x), w2, a0); a1 = fmaf(bfhi(v2.x), w2, a1);
        a2 = fmaf(bflo(v2.y), w2, a2); a3 = fmaf(bfhi(v2.y), w2, a3);
    }

    a0 += __shfl_xor(a0, 16); a1 += __shfl_xor(a1, 16);
    a2 += __shfl_xor(a2, 16); a3 += __shfl_xor(a3, 16);
    a0 += __shfl_xor(a0, 32); a1 += __shfl_xor(a1, 32);
    a2 += __shfl_xor(a2, 32); a3 += __shfl_xor(a3, 32);
    if (q == 0) {
        float sc = dinv[n];
        float4 b = *(const float4*)&bias[4 * s];
        float4 o;
        o.x = fmaf(a0, sc, b.x); o.y = fmaf(a1, sc, b.y);
        o.z = fmaf(a2, sc, b.z); o.w = fmaf(a3, sc, b.w);
        *(float4*)&out[(size_t)n * 64 + 4 * s] = o;
    }
}

extern "C" void kernel_launch(void* const* d_in, const int* in_sizes, int n_in,
                              void* d_out, int out_size, void* d_ws, size_t ws_size,
                              hipStream_t stream) {
    const float* x  = (const float*)d_in[0];
    const int*   ei = (const int*)d_in[1];
    const float* W1 = (const float*)d_in[2];
    const float* b1 = (const float*)d_in[3];
    const float* W2 = (const float*)d_in[4];
    const float* b2 = (const float*)d_in[5];
    float* out = (float*)d_out;

    const int N = in_sizes[0] / 128;   // 100000
    const int E = in_sizes[1] / 2;     // 800000
    const int* src = ei;
    const int* dst = ei + E;
    const int NPAD = (N + 63) & ~63;

    const int NBLK_A = (E + CHUNK - 1) / CHUNK;        // 196
    const int L      = NBUCKP * NBLK_A;                // 100352
    const int NBLK_S = (L + 255) / 256;                // 392  (<=512)
    const int NBUCK  = (N + 255) / 256;                // 391

    // workspace layout (4-byte units)
    unsigned off = 0;
    int* row_ptr    = (int*)d_ws + off;            off += NPAD + 64;
    float* dinv     = (float*)((int*)d_ws + off);  off += NPAD + 64;
    int* ghist      = (int*)d_ws + off;            off += (unsigned)((L + 63) & ~63);
    int* part       = (int*)d_ws + off;            off += 512;
    unsigned* eb    = (unsigned*)((int*)d_ws + off); off += (unsigned)((E + 63) & ~63);
    int* col        = (int*)d_ws + off;            off += (unsigned)((E + 63) & ~63);
    unsigned short* W1t = (unsigned short*)((int*)d_ws + off); off += 8192;
    unsigned short* W2t = (unsigned short*)((int*)d_ws + off); off += 4096;
    unsigned* H     = (unsigned*)((int*)d_ws + off); off += (unsigned)N * 64 + 64;
    unsigned* act   = (unsigned*)((int*)d_ws + off);

    // CSR build (no global atomics)
    k_hist<<<NBLK_A, 256, 0, stream>>>(dst, ghist, E, NBLK_A);
    k_part<<<NBLK_S, 256, 0, stream>>>(ghist, part, L);
    k_scanpart<<<1, 512, 0, stream>>>(part, NBLK_S);
    k_scan_apply<<<NBLK_S, 256, 0, stream>>>(ghist, part, L);
    k_scatter_part<<<NBLK_A, 256, 0, stream>>>(src, dst, ghist, eb, E, NBLK_A);
    k_bucket_csr<<<NBUCK, 256, 0, stream>>>(eb, ghist, row_ptr, dinv, col, E, NBLK_A, N);
    k_prep_w<<<96, 256, 0, stream>>>(W1, W2, W1t, W2t);

    // Layer 1
    k_gemm<128, false><<<(N + 63) / 64, 256, 0, stream>>>(x, W1t, dinv,
                                                          (unsigned short*)H, N);
    k_gather128<true><<<(N + 3) / 4, 256, 0, stream>>>(H, row_ptr, col, dinv, b1, act, N);

    // Layer 2
    k_gemm<64, true><<<(N + 63) / 64, 256, 0, stream>>>(act, W2t, dinv,
                                                        (unsigned short*)H, N);
    k_gather64<<<(N + 3) / 4, 256, 0, stream>>>(H, row_ptr, col, dinv, b2, out, N);
}

// Round 7
// 153.567 us; speedup vs baseline: 14.2044x; 1.0099x over previous
//
#include <hip/hip_runtime.h>

// WalletGNN: 2-layer GCN, N=100000, E=800000, 128 -> 128 -> 64, fp32 in/out.
// R7: gather accumulate path halved — raw-word "hi" bf16 (skip v_and; junk
//     mantissa < 2^-8 relative) + f32x4 accumulators to get v_pk_add_f32 /
//     v_pk_fma_f32. prep_w fused into k_hist (one fewer dispatch).

typedef __attribute__((ext_vector_type(8))) short bf16x8;
typedef __attribute__((ext_vector_type(4))) float f32x4;

static __device__ __forceinline__ unsigned short f2bf(float f) {
    unsigned u = __builtin_bit_cast(unsigned, f);
    u += 0x7fffu + ((u >> 16) & 1u);
    return (unsigned short)(u >> 16);
}
static __device__ __forceinline__ float bflo(unsigned u) {
    return __builtin_bit_cast(float, u << 16);
}
// {lo(x), hi(x)+junk, lo(y), hi(y)+junk} — skips the 0xffff0000 mask;
// junk mantissa bits are < 2^-8 relative (same order as bf16 rounding).
static __device__ __forceinline__ f32x4 bfquad(uint2 v) {
    f32x4 r;
    r[0] = bflo(v.x); r[1] = __builtin_bit_cast(float, v.x);
    r[2] = bflo(v.y); r[3] = __builtin_bit_cast(float, v.y);
    return r;
}

#define CHUNK 4096              // edges per partition block
#define NBUCKP 512              // padded bucket count (dst>>8 < 391)

// ---------- A1: per-block bucket histogram (+fused W^T bf16 prep) ----------
__global__ __launch_bounds__(256) void k_hist(const int* __restrict__ dst,
        int* __restrict__ ghist, int E, int nblk,
        const float* __restrict__ W1, const float* __restrict__ W2,
        unsigned short* __restrict__ W1t, unsigned short* __restrict__ W2t) {
    __shared__ int h[NBUCKP];
    const int tid = threadIdx.x, b = blockIdx.x;
    if (b >= nblk) {            // prep_w blocks
        int i = (b - nblk) * 256 + tid;
        if (i < 128 * 128) {
            int n = i >> 7, k = i & 127;
            W1t[i] = f2bf(W1[k * 128 + n]);
        }
        int j = i - 128 * 128;
        if (j >= 0 && j < 64 * 128) {
            int n = j >> 7, k = j & 127;
            W2t[j] = f2bf(W2[k * 64 + n]);
        }
        return;
    }
    h[tid] = 0; h[tid + 256] = 0;
    __syncthreads();
    const int base = b * CHUNK;
#pragma unroll
    for (int i = 0; i < CHUNK / 256; ++i) {
        int e = base + i * 256 + tid;
        if (e < E) atomicAdd(&h[dst[e] >> 8], 1);
    }
    __syncthreads();
    ghist[tid * nblk + b] = h[tid];
    ghist[(tid + 256) * nblk + b] = h[tid + 256];
}

// ---------- hierarchical scan helpers ----------
__global__ __launch_bounds__(256) void k_part(const int* __restrict__ v,
                                              int* __restrict__ part, int L) {
    __shared__ int s[256];
    int tid = threadIdx.x;
    int i = blockIdx.x * 256 + tid;
    s[tid] = (i < L) ? v[i] : 0;
    __syncthreads();
    for (int o = 128; o > 0; o >>= 1) {
        if (tid < o) s[tid] += s[tid + o];
        __syncthreads();
    }
    if (tid == 0) part[blockIdx.x] = s[0];
}

__global__ __launch_bounds__(512) void k_scanpart(int* __restrict__ part, int nb) {
    __shared__ int s[512];
    int tid = threadIdx.x;
    int v = (tid < nb) ? part[tid] : 0;
    s[tid] = v;
    __syncthreads();
    for (int off = 1; off < 512; off <<= 1) {
        int t = (tid >= off) ? s[tid - off] : 0;
        __syncthreads();
        s[tid] += t;
        __syncthreads();
    }
    if (tid < nb) part[tid] = s[tid] - v;   // exclusive
}

__global__ __launch_bounds__(256) void k_scan_apply(int* __restrict__ v,
        const int* __restrict__ part, int L) {
    __shared__ int s[256];
    int tid = threadIdx.x;
    int i = blockIdx.x * 256 + tid;
    int x = (i < L) ? v[i] : 0;
    s[tid] = x;
    __syncthreads();
    for (int off = 1; off < 256; off <<= 1) {
        int t = (tid >= off) ? s[tid - off] : 0;
        __syncthreads();
        s[tid] += t;
        __syncthreads();
    }
    if (i < L) v[i] = part[blockIdx.x] + s[tid] - x;
}

// ---------- A3: partition scatter via LDS cursors (packed uint32) ----------
__global__ __launch_bounds__(256) void k_scatter_part(const int* __restrict__ src,
        const int* __restrict__ dst, const int* __restrict__ S,
        unsigned* __restrict__ eb, int E, int nblk) {
    __shared__ int cur[NBUCKP];
    const int tid = threadIdx.x, b = blockIdx.x;
    cur[tid] = S[tid * nblk + b];
    cur[tid + 256] = S[(tid + 256) * nblk + b];
    __syncthreads();
    const int base = b * CHUNK;
#pragma unroll
    for (int i = 0; i < CHUNK / 256; ++i) {
        int e = base + i * 256 + tid;
        if (e < E) {
            int s = src[e], d = dst[e];
            int pos = atomicAdd(&cur[d >> 8], 1);
            eb[pos] = ((unsigned)(d & 255) << 24) | (unsigned)s;
        }
    }
}

// ---------- B: per-bucket CSR finalize (256 dst values per block) ----------
__global__ __launch_bounds__(256) void k_bucket_csr(const unsigned* __restrict__ eb,
        const int* __restrict__ S, int* __restrict__ row_ptr,
        float* __restrict__ dinv, int* __restrict__ col, int E, int nblk, int N) {
    __shared__ int h[256], sc[256], cur[256];
    const int tid = threadIdx.x, k = blockIdx.x;
    const int bstart = S[k * nblk];
    const int bend   = S[(k + 1) * nblk];
    h[tid] = 0;
    __syncthreads();
    for (int e = bstart + tid; e < bend; e += 256)
        atomicAdd(&h[eb[e] >> 24], 1);
    __syncthreads();
    int v = h[tid];
    sc[tid] = v;
    __syncthreads();
    for (int off = 1; off < 256; off <<= 1) {
        int t = (tid >= off) ? sc[tid - off] : 0;
        __syncthreads();
        sc[tid] += t;
        __syncthreads();
    }
    int excl = sc[tid] - v;
    int n = k * 256 + tid;
    if (n < N) {
        row_ptr[n] = bstart + excl;
        dinv[n] = rsqrtf((float)v + 1.0f);    // +1 self-loop
        if (n == N - 1) row_ptr[N] = bstart + excl + v;
    }
    cur[tid] = excl;
    __syncthreads();
    for (int e = bstart + tid; e < bend; e += 256) {
        unsigned ed = eb[e];
        int pos = bstart + atomicAdd(&cur[ed >> 24], 1);
        col[pos] = (int)(ed & 0xFFFFFFu);
    }
}

// ---------- MFMA GEMM: C[r][:] = bf16( dinv[r] * (A[r][:] @ B) ), K=128 ----------
template<int NC, bool ABF16>
__global__ __launch_bounds__(256) void k_gemm(const void* __restrict__ Av,
        const unsigned short* __restrict__ Wt, const float* __restrict__ dinv,
        unsigned short* __restrict__ C, int M) {
    __shared__ unsigned short sA[64][136];
    __shared__ unsigned short sW[NC][136];
    const int tid  = threadIdx.x;
    const int lane = tid & 63;
    const int wave = tid >> 6;
    const int row0 = blockIdx.x * 64;

    if (ABF16) {
        const uint4* A = (const uint4*)Av;
#pragma unroll
        for (int p = 0; p < 4; ++p) {
            int c = tid + p * 256;
            int row = c >> 4, cc = c & 15;
            uint4 v = make_uint4(0u, 0u, 0u, 0u);
            if (row0 + row < M) v = A[(size_t)(row0 + row) * 16 + cc];
            *(uint4*)&sA[row][cc * 8] = v;
        }
    } else {
        const float* A = (const float*)Av;
#pragma unroll
        for (int p = 0; p < 8; ++p) {
            int c = tid + p * 256;
            int row = c >> 5, c4 = (c & 31) * 4;
            float4 v = make_float4(0.f, 0.f, 0.f, 0.f);
            if (row0 + row < M) v = *(const float4*)&A[(size_t)(row0 + row) * 128 + c4];
            ushort4 o;
            o.x = f2bf(v.x); o.y = f2bf(v.y); o.z = f2bf(v.z); o.w = f2bf(v.w);
            *(ushort4*)&sA[row][c4] = o;
        }
    }
    {
        const uint4* W4 = (const uint4*)Wt;
#pragma unroll
        for (int p = 0; p < NC / 16; ++p) {
            int c = tid + p * 256;
            int n = c >> 4, cc = c & 15;
            *(uint4*)&sW[n][cc * 8] = W4[c];
        }
    }
    __syncthreads();

    constexpr int CT = NC / 64;
    const int colbase = wave * (NC / 4);
    const int frow = lane & 15;
    const int fk   = (lane >> 4) * 8;

    f32x4 acc[4][CT];
#pragma unroll
    for (int rt = 0; rt < 4; ++rt)
#pragma unroll
        for (int ct = 0; ct < CT; ++ct) acc[rt][ct] = (f32x4){0.f, 0.f, 0.f, 0.f};

#pragma unroll
    for (int kk = 0; kk < 128; kk += 32) {
        bf16x8 a[4], b[CT];
#pragma unroll
        for (int rt = 0; rt < 4; ++rt)
            a[rt] = *(const bf16x8*)&sA[rt * 16 + frow][kk + fk];
#pragma unroll
        for (int ct = 0; ct < CT; ++ct)
            b[ct] = *(const bf16x8*)&sW[colbase + ct * 16 + frow][kk + fk];
#pragma unroll
        for (int rt = 0; rt < 4; ++rt)
#pragma unroll
            for (int ct = 0; ct < CT; ++ct)
                acc[rt][ct] = __builtin_amdgcn_mfma_f32_16x16x32_bf16(
                    a[rt], b[ct], acc[rt][ct], 0, 0, 0);
    }

    const int crow = (lane >> 4) * 4;
#pragma unroll
    for (int rt = 0; rt < 4; ++rt) {
        int grow = row0 + rt * 16 + crow;
#pragma unroll
        for (int r = 0; r < 4; ++r) {
            if (grow + r < M) {
                float s = dinv[grow + r];
#pragma unroll
                for (int ct = 0; ct < CT; ++ct) {
                    int gcol = colbase + ct * 16 + (lane & 15);
                    C[(size_t)(grow + r) * NC + gcol] = f2bf(acc[rt][ct][r] * s);
                }
            }
        }
    }
}

// ---------- gather D=128: wave/node, half-wave slices, pk accumulate ----------
template<bool ELU>
__global__ __launch_bounds__(256) void k_gather128(const unsigned* __restrict__ H,
        const int* __restrict__ row_ptr, const int* __restrict__ col,
        const float* __restrict__ dinv, const float* __restrict__ bias,
        unsigned* __restrict__ outbf, int N) {
    const int wave = threadIdx.x >> 6, lane = threadIdx.x & 63;
    const int n = blockIdx.x * 4 + wave;
    if (n >= N) return;
    const int beg = row_ptr[n], end = row_ptr[n + 1];
    const int half = lane >> 5;
    const int s = lane & 31;
    f32x4 acc = (f32x4){0.f, 0.f, 0.f, 0.f};

    if (half == 0) {                            // self row
        uint2 v = *(const uint2*)&H[(size_t)n * 64 + 2 * s];
        acc += bfquad(v);
    }
    int j = beg + half;
    for (; j + 6 < end; j += 8) {               // 4 neighbors in flight per half
        int c0 = col[j], c1 = col[j + 2], c2 = col[j + 4], c3 = col[j + 6];
        uint2 v0 = *(const uint2*)&H[(size_t)c0 * 64 + 2 * s];
        uint2 v1 = *(const uint2*)&H[(size_t)c1 * 64 + 2 * s];
        uint2 v2 = *(const uint2*)&H[(size_t)c2 * 64 + 2 * s];
        uint2 v3 = *(const uint2*)&H[(size_t)c3 * 64 + 2 * s];
        acc += bfquad(v0);
        acc += bfquad(v1);
        acc += bfquad(v2);
        acc += bfquad(v3);
    }
    if (j < end) {                              // predicated tail (<=3 items)
        const int e1 = end - 1;
        int j1 = j + 2, j2 = j + 4;
        int c0 = col[j];
        int c1 = col[j1 <= e1 ? j1 : e1];       // clamped: cache-hot row
        int c2 = col[j2 <= e1 ? j2 : e1];
        float w1 = (j1 < end) ? 1.f : 0.f;
        float w2 = (j2 < end) ? 1.f : 0.f;
        uint2 v0 = *(const uint2*)&H[(size_t)c0 * 64 + 2 * s];
        uint2 v1 = *(const uint2*)&H[(size_t)c1 * 64 + 2 * s];
        uint2 v2 = *(const uint2*)&H[(size_t)c2 * 64 + 2 * s];
        acc += bfquad(v0);
        acc += bfquad(v1) * w1;
        acc += bfquad(v2) * w2;
    }

    float a0 = acc[0], a1 = acc[1], a2 = acc[2], a3 = acc[3];
    a0 += __shfl_xor(a0, 32); a1 += __shfl_xor(a1, 32);
    a2 += __shfl_xor(a2, 32); a3 += __shfl_xor(a3, 32);
    if (half == 0) {
        float sc = dinv[n];
        float4 b = *(const float4*)&bias[4 * s];
        float o0 = fmaf(a0, sc, b.x), o1 = fmaf(a1, sc, b.y);
        float o2 = fmaf(a2, sc, b.z), o3 = fmaf(a3, sc, b.w);
        if (ELU) {
            o0 = o0 > 0.f ? o0 : expm1f(o0);
            o1 = o1 > 0.f ? o1 : expm1f(o1);
            o2 = o2 > 0.f ? o2 : expm1f(o2);
            o3 = o3 > 0.f ? o3 : expm1f(o3);
        }
        uint2 o;
        o.x = (unsigned)f2bf(o0) | ((unsigned)f2bf(o1) << 16);
        o.y = (unsigned)f2bf(o2) | ((unsigned)f2bf(o3) << 16);
        *(uint2*)&outbf[(size_t)n * 64 + 2 * s] = o;
    }
}

// ---------- gather D=64: quarter-wave slices, 4-deep, pk accumulate ----------
__global__ __launch_bounds__(256) void k_gather64(const unsigned* __restrict__ H,
        const int* __restrict__ row_ptr, const int* __restrict__ col,
        const float* __restrict__ dinv, const float* __restrict__ bias,
        float* __restrict__ out, int N) {
    const int wave = threadIdx.x >> 6, lane = threadIdx.x & 63;
    const int n = blockIdx.x * 4 + wave;
    if (n >= N) return;
    const int beg = row_ptr[n], end = row_ptr[n + 1];
    const int q = lane >> 4;
    const int s = lane & 15;
    f32x4 acc = (f32x4){0.f, 0.f, 0.f, 0.f};

    if (q == 0) {                               // self row
        uint2 v = *(const uint2*)&H[(size_t)n * 32 + 2 * s];
        acc += bfquad(v);
    }
    int j = beg + q;
    for (; j + 12 < end; j += 16) {             // 4 neighbors in flight per quarter
        int c0 = col[j], c1 = col[j + 4], c2 = col[j + 8], c3 = col[j + 12];
        uint2 v0 = *(const uint2*)&H[(size_t)c0 * 32 + 2 * s];
        uint2 v1 = *(const uint2*)&H[(size_t)c1 * 32 + 2 * s];
        uint2 v2 = *(const uint2*)&H[(size_t)c2 * 32 + 2 * s];
        uint2 v3 = *(const uint2*)&H[(size_t)c3 * 32 + 2 * s];
        acc += bfquad(v0);
        acc += bfquad(v1);
        acc += bfquad(v2);
        acc += bfquad(v3);
    }
    if (j < end) {                              // predicated tail (<=3 items)
        const int e1 = end - 1;
        int j1 = j + 4, j2 = j + 8;
        int c0 = col[j];
        int c1 = col[j1 <= e1 ? j1 : e1];
        int c2 = col[j2 <= e1 ? j2 : e1];
        float w1 = (j1 < end) ? 1.f : 0.f;
        float w2 = (j2 < end) ? 1.f : 0.f;
        uint2 v0 = *(const uint2*)&H[(size_t)c0 * 32 + 2 * s];
        uint2 v1 = *(const uint2*)&H[(size_t)c1 * 32 + 2 * s];
        uint2 v2 = *(const uint2*)&H[(size_t)c2 * 32 + 2 * s];
        acc += bfquad(v0);
        acc += bfquad(v1) * w1;
        acc += bfquad(v2) * w2;
    }

    float a0 = acc[0], a1 = acc[1], a2 = acc[2], a3 = acc[3];
    a0 += __shfl_xor(a0, 16); a1 += __shfl_xor(a1, 16);
    a2 += __shfl_xor(a2, 16); a3 += __shfl_xor(a3, 16);
    a0 += __shfl_xor(a0, 32); a1 += __shfl_xor(a1, 32);
    a2 += __shfl_xor(a2, 32); a3 += __shfl_xor(a3, 32);
    if (q == 0) {
        float sc = dinv[n];
        float4 b = *(const float4*)&bias[4 * s];
        float4 o;
        o.x = fmaf(a0, sc, b.x); o.y = fmaf(a1, sc, b.y);
        o.z = fmaf(a2, sc, b.z); o.w = fmaf(a3, sc, b.w);
        *(float4*)&out[(size_t)n * 64 + 4 * s] = o;
    }
}

extern "C" void kernel_launch(void* const* d_in, const int* in_sizes, int n_in,
                              void* d_out, int out_size, void* d_ws, size_t ws_size,
                              hipStream_t stream) {
    const float* x  = (const float*)d_in[0];
    const int*   ei = (const int*)d_in[1];
    const float* W1 = (const float*)d_in[2];
    const float* b1 = (const float*)d_in[3];
    const float* W2 = (const float*)d_in[4];
    const float* b2 = (const float*)d_in[5];
    float* out = (float*)d_out;

    const int N = in_sizes[0] / 128;   // 100000
    const int E = in_sizes[1] / 2;     // 800000
    const int* src = ei;
    const int* dst = ei + E;
    const int NPAD = (N + 63) & ~63;

    const int NBLK_A = (E + CHUNK - 1) / CHUNK;        // 196
    const int L      = NBUCKP * NBLK_A;                // 100352
    const int NBLK_S = (L + 255) / 256;                // 392  (<=512)
    const int NBUCK  = (N + 255) / 256;                // 391

    // workspace layout (4-byte units)
    unsigned off = 0;
    int* row_ptr    = (int*)d_ws + off;            off += NPAD + 64;
    float* dinv     = (float*)((int*)d_ws + off);  off += NPAD + 64;
    int* ghist      = (int*)d_ws + off;            off += (unsigned)((L + 63) & ~63);
    int* part       = (int*)d_ws + off;            off += 512;
    unsigned* eb    = (unsigned*)((int*)d_ws + off); off += (unsigned)((E + 63) & ~63);
    int* col        = (int*)d_ws + off;            off += (unsigned)((E + 63) & ~63);
    unsigned short* W1t = (unsigned short*)((int*)d_ws + off); off += 8192;
    unsigned short* W2t = (unsigned short*)((int*)d_ws + off); off += 4096;
    unsigned* H     = (unsigned*)((int*)d_ws + off); off += (unsigned)N * 64 + 64;
    unsigned* act   = (unsigned*)((int*)d_ws + off);

    // CSR build (no global atomics) + fused W prep
    k_hist<<<NBLK_A + 96, 256, 0, stream>>>(dst, ghist, E, NBLK_A, W1, W2, W1t, W2t);
    k_part<<<NBLK_S, 256, 0, stream>>>(ghist, part, L);
    k_scanpart<<<1, 512, 0, stream>>>(part, NBLK_S);
    k_scan_apply<<<NBLK_S, 256, 0, stream>>>(ghist, part, L);
    k_scatter_part<<<NBLK_A, 256, 0, stream>>>(src, dst, ghist, eb, E, NBLK_A);
    k_bucket_csr<<<NBUCK, 256, 0, stream>>>(eb, ghist, row_ptr, dinv, col, E, NBLK_A, N);

    // Layer 1
    k_gemm<128, false><<<(N + 63) / 64, 256, 0, stream>>>(x, W1t, dinv,
                                                          (unsigned short*)H, N);
    k_gather128<true><<<(N + 3) / 4, 256, 0, stream>>>(H, row_ptr, col, dinv, b1, act, N);

    // Layer 2
    k_gemm<64, true><<<(N + 63) / 64, 256, 0, stream>>>(act, W2t, dinv,
                                                        (unsigned short*)H, N);
    k_gather64<<<(N + 3) / 4, 256, 0, stream>>>(H, row_ptr, col, dinv, b2, out, N);
}